// Round 6
// baseline (6852.060 us; speedup 1.0000x reference)
//
#include <hip/hip_runtime.h>

#define D 128
#define NT 10    // edge types
#define NL 4     // layers
#define SCH 1024 // nodes per scan chunk
#define NMAT 57
#define MATSZ 32768  // shorts per converted matrix (hi 16384 + lo 16384)

typedef __attribute__((ext_vector_type(8))) short bf16x8;
typedef __attribute__((ext_vector_type(4))) float f32x4;

struct CvtTab { const float* src[NMAT]; int ldw[NMAT]; };

__device__ inline unsigned short f2bf(float x) {
    union { float f; unsigned u; } v; v.f = x;
    unsigned r = v.u + 0x7FFFu + ((v.u >> 16) & 1u);
    return (unsigned short)(r >> 16);
}
__device__ inline float bf2f(unsigned short h) {
    union { unsigned u; float f; } v; v.u = ((unsigned)h) << 16;
    return v.f;
}
__device__ inline void cvt8(const float4& v0, const float4& v1, bf16x8& h,
                            bf16x8& l) {
    float f[8] = {v0.x, v0.y, v0.z, v0.w, v1.x, v1.y, v1.z, v1.w};
#pragma unroll
    for (int j = 0; j < 8; ++j) {
        unsigned short hh = f2bf(f[j]);
        h[j] = (short)hh;
        l[j] = (short)f2bf(f[j] - bf2f(hh));
    }
}
__device__ inline f32x4 MF(bf16x8 a, bf16x8 b, f32x4 c) {
    return __builtin_amdgcn_mfma_f32_16x16x32_bf16(a, b, c, 0, 0, 0);
}

// XOR-granule swizzle for the 128x128 fp32 LDS tile (64 KB): spreads the
// stride-512B column reads across 8 bank-quads (G4: stride-128 is 16-way).
__device__ inline int gsw(int row, int c) {
    return (row << 7) + (((((c >> 2) ^ ((row & 7) << 2)) & 31) << 2) | (c & 3));
}

// MFMA pass, A = 32 fp32 rows [rowb..rowb+32) of the swizzled LDS tile
__device__ inline void pass_lds(f32x4 (&acc)[2][8], const float* G, int rowb,
                                const unsigned short* Wm, int fr, int fq) {
#pragma unroll
    for (int kc = 0; kc < 4; ++kc) {
        int ko = kc * 32 + fq * 8;
        bf16x8 ah[2], al[2];
#pragma unroll
        for (int m = 0; m < 2; ++m) {
            int row = rowb + m * 16 + fr;
            float4 v0 = *(const float4*)(G + gsw(row, ko));
            float4 v1 = *(const float4*)(G + gsw(row, ko + 4));
            cvt8(v0, v1, ah[m], al[m]);
        }
#pragma unroll
        for (int n = 0; n < 8; ++n) {
            const unsigned short* wp = Wm + (size_t)(n * 16 + fr) * D + ko;
            bf16x8 wh = *(const bf16x8*)wp;
            bf16x8 wl = *(const bf16x8*)(wp + 16384);
#pragma unroll
            for (int m = 0; m < 2; ++m) {
                acc[m][n] = MF(ah[m], wh, acc[m][n]);
                acc[m][n] = MF(ah[m], wl, acc[m][n]);
                acc[m][n] = MF(al[m], wh, acc[m][n]);
            }
        }
    }
}

// MFMA pass, A = fp32 rows straight from global (row-guarded)
__device__ inline void pass_glb(f32x4 (&acc)[2][8], const float* A, int rbase,
                                int N, const unsigned short* Wm, int fr,
                                int fq) {
    int r0 = rbase + fr, r1 = rbase + 16 + fr;
    const float* a0 = A + (size_t)r0 * D;
    const float* a1 = A + (size_t)r1 * D;
    bool ok0 = r0 < N, ok1 = r1 < N;
#pragma unroll
    for (int kc = 0; kc < 4; ++kc) {
        int ko = kc * 32 + fq * 8;
        bf16x8 ah[2], al[2];
        float4 v0 = {0, 0, 0, 0}, v1 = {0, 0, 0, 0};
        if (ok0) { v0 = *(const float4*)(a0 + ko); v1 = *(const float4*)(a0 + ko + 4); }
        cvt8(v0, v1, ah[0], al[0]);
        float4 u0 = {0, 0, 0, 0}, u1 = {0, 0, 0, 0};
        if (ok1) { u0 = *(const float4*)(a1 + ko); u1 = *(const float4*)(a1 + ko + 4); }
        cvt8(u0, u1, ah[1], al[1]);
#pragma unroll
        for (int n = 0; n < 8; ++n) {
            const unsigned short* wp = Wm + (size_t)(n * 16 + fr) * D + ko;
            bf16x8 wh = *(const bf16x8*)wp;
            bf16x8 wl = *(const bf16x8*)(wp + 16384);
#pragma unroll
            for (int m = 0; m < 2; ++m) {
                acc[m][n] = MF(ah[m], wh, acc[m][n]);
                acc[m][n] = MF(ah[m], wl, acc[m][n]);
                acc[m][n] = MF(al[m], wh, acc[m][n]);
            }
        }
    }
}

__device__ inline void zero_acc(f32x4 (&acc)[2][8]) {
#pragma unroll
    for (int m = 0; m < 2; ++m)
#pragma unroll
        for (int n = 0; n < 8; ++n) acc[m][n] = (f32x4){0.f, 0.f, 0.f, 0.f};
}

// write acc (C layout: row=m*16+fq*4+j, col=n*16+fr) into the LDS tile
__device__ inline void store_lds_C(const f32x4 (&acc)[2][8], float* G,
                                   int rowb, int fr, int fq) {
#pragma unroll
    for (int m = 0; m < 2; ++m)
#pragma unroll
        for (int j = 0; j < 4; ++j) {
            int row = rowb + m * 16 + fq * 4 + j;
#pragma unroll
            for (int n = 0; n < 8; ++n) G[gsw(row, n * 16 + fr)] = acc[m][n][j];
        }
}

// ---------------------------------------------------------------------------
// Fused layer: temp = F@Wc + edge-aggregates; GroupNorm+relu; MLP; residual.
// Each wave owns 32 rows end-to-end: no barriers.
// ---------------------------------------------------------------------------
__global__ __launch_bounds__(256) void layer_fused_kernel(
    const float* __restrict__ Fin, float* __restrict__ Fout,
    const unsigned short* __restrict__ Wcvt, int li,
    const int* __restrict__ rowptr, const int* __restrict__ col,
    const float* __restrict__ ng, const float* __restrict__ nb,
    const float* __restrict__ mb1, const float* __restrict__ mb2, int N,
    int E) {
    __shared__ float G[128 * 128];
    int t = threadIdx.x, wave = t >> 6, lane = t & 63;
    int fr = lane & 15, fq = lane >> 4;
    int n0 = blockIdx.x * 128;
    int rbase = n0 + wave * 32;
    int rowb = wave * 32;

    f32x4 acc[2][8];
    zero_acc(acc);

    const unsigned short* WL = Wcvt + (size_t)(10 + li * 11) * MATSZ;
    // ctr term: A = Fin rows streamed from global
    pass_glb(acc, Fin, rbase, N, WL + (size_t)10 * MATSZ, fr, fq);

    // 10 edge types: gather neighbor-sum into LDS, MFMA into acc
    for (int tt = 0; tt < NT; ++tt) {
        const int* rp = rowptr + (size_t)tt * (N + 1);
        const int* cj = col + (size_t)tt * E;
        for (int r4 = 0; r4 < 32; r4 += 4) {
            int u0 = rbase + r4;
            int p[5];
#pragma unroll
            for (int q = 0; q < 5; ++q) p[q] = rp[min(u0 + q, N)];
            int c0 = p[1] - p[0], c1 = p[2] - p[1], c2 = p[3] - p[2],
                c3 = p[4] - p[3];
            float2 s0 = {0, 0}, s1 = {0, 0}, s2 = {0, 0}, s3 = {0, 0};
            int mx = max(max(c0, c1), max(c2, c3));
            int lc = lane << 1;
            for (int k = 0; k < mx; ++k) {
                if (k < c0) { int v = cj[p[0] + k]; float2 y = *(const float2*)&Fin[(size_t)v * D + lc]; s0.x += y.x; s0.y += y.y; }
                if (k < c1) { int v = cj[p[1] + k]; float2 y = *(const float2*)&Fin[(size_t)v * D + lc]; s1.x += y.x; s1.y += y.y; }
                if (k < c2) { int v = cj[p[2] + k]; float2 y = *(const float2*)&Fin[(size_t)v * D + lc]; s2.x += y.x; s2.y += y.y; }
                if (k < c3) { int v = cj[p[3] + k]; float2 y = *(const float2*)&Fin[(size_t)v * D + lc]; s3.x += y.x; s3.y += y.y; }
            }
            *(float2*)(G + gsw(rowb + r4 + 0, lc)) = s0;
            *(float2*)(G + gsw(rowb + r4 + 1, lc)) = s1;
            *(float2*)(G + gsw(rowb + r4 + 2, lc)) = s2;
            *(float2*)(G + gsw(rowb + r4 + 3, lc)) = s3;
        }
        pass_lds(acc, G, rowb, WL + (size_t)tt * MATSZ, fr, fq);
    }

    // GroupNorm(1,D) + affine + relu, fully in-register
    float gv[8], bv[8];
#pragma unroll
    for (int n = 0; n < 8; ++n) { gv[n] = ng[n * 16 + fr]; bv[n] = nb[n * 16 + fr]; }
#pragma unroll
    for (int m = 0; m < 2; ++m)
#pragma unroll
        for (int j = 0; j < 4; ++j) {
            float s = 0.f, q = 0.f;
#pragma unroll
            for (int n = 0; n < 8; ++n) { float x = acc[m][n][j]; s += x; q += x * x; }
#pragma unroll
            for (int o = 1; o <= 8; o <<= 1) { s += __shfl_xor(s, o); q += __shfl_xor(q, o); }
            float mu = s * (1.f / 128.f);
            float var = q * (1.f / 128.f) - mu * mu;
            float rs = rsqrtf(var + 1e-5f);
#pragma unroll
            for (int n = 0; n < 8; ++n)
                acc[m][n][j] = fmaxf(fmaf((acc[m][n][j] - mu) * rs, gv[n], bv[n]), 0.f);
        }

    // MLP1: H = relu(T@W1 + b1)   (T bounced through LDS, wave-local)
    store_lds_C(acc, G, rowb, fr, fq);
    zero_acc(acc);
    pass_lds(acc, G, rowb, Wcvt + (size_t)(2 + li) * MATSZ, fr, fq);
    float b1v[8], b2v[8];
#pragma unroll
    for (int n = 0; n < 8; ++n) { b1v[n] = mb1[n * 16 + fr]; b2v[n] = mb2[n * 16 + fr]; }
#pragma unroll
    for (int m = 0; m < 2; ++m)
#pragma unroll
        for (int n = 0; n < 8; ++n)
#pragma unroll
            for (int j = 0; j < 4; ++j)
                acc[m][n][j] = fmaxf(acc[m][n][j] + b1v[n], 0.f);

    // MLP2 + residual + relu
    store_lds_C(acc, G, rowb, fr, fq);
    zero_acc(acc);
    pass_lds(acc, G, rowb, Wcvt + (size_t)(6 + li) * MATSZ, fr, fq);
#pragma unroll
    for (int m = 0; m < 2; ++m)
#pragma unroll
        for (int j = 0; j < 4; ++j) {
            int row = rbase + m * 16 + fq * 4 + j;
            if (row < N) {
#pragma unroll
                for (int n = 0; n < 8; ++n) {
                    int c = n * 16 + fr;
                    float r = acc[m][n][j] + b2v[n] + Fin[(size_t)row * D + c];
                    Fout[(size_t)row * D + c] = fmaxf(r, 0.f);
                }
            }
        }
}

// ---------------------------------------------------------------------------
// Fused input: F = relu(h1@W2_in + b_in2 + h2@W2_seg + b_seg2), h from K=2 MLPs
// ---------------------------------------------------------------------------
__global__ __launch_bounds__(256) void input_fused_kernel(
    const float* __restrict__ ctrs, const float* __restrict__ feats,
    const float* __restrict__ inW1, const float* __restrict__ inb1,
    const float* __restrict__ segW1, const float* __restrict__ segb1,
    const float* __restrict__ inb2, const float* __restrict__ segb2,
    const unsigned short* __restrict__ Wcvt, float* __restrict__ Fout, int N) {
    __shared__ float G[128 * 128];
    int t = threadIdx.x, wave = t >> 6, lane = t & 63;
    int fr = lane & 15, fq = lane >> 4;
    int rbase = blockIdx.x * 128 + wave * 32;
    int rowb = wave * 32;
    int c0 = lane * 2;

    float iw0 = inW1[2 * c0], iw1 = inW1[2 * c0 + 1], iw2 = inW1[2 * c0 + 2],
          iw3 = inW1[2 * c0 + 3];
    float ib0 = inb1[c0], ib1 = inb1[c0 + 1];
    float sw0 = segW1[2 * c0], sw1 = segW1[2 * c0 + 1], sw2 = segW1[2 * c0 + 2],
          sw3 = segW1[2 * c0 + 3];
    float sb0 = segb1[c0], sb1 = segb1[c0 + 1];

    f32x4 acc[2][8];
    zero_acc(acc);

    for (int r = 0; r < 32; ++r) {
        int u = rbase + r;
        float2 h = {0.f, 0.f};
        if (u < N) {
            float2 x = *(const float2*)&ctrs[2 * (size_t)u];
            h.x = fmaxf(fmaf(x.x, iw0, fmaf(x.y, iw1, ib0)), 0.f);
            h.y = fmaxf(fmaf(x.x, iw2, fmaf(x.y, iw3, ib1)), 0.f);
        }
        *(float2*)(G + gsw(rowb + r, c0)) = h;
    }
    pass_lds(acc, G, rowb, Wcvt + (size_t)0 * MATSZ, fr, fq);

    for (int r = 0; r < 32; ++r) {
        int u = rbase + r;
        float2 h = {0.f, 0.f};
        if (u < N) {
            float2 x = *(const float2*)&feats[2 * (size_t)u];
            h.x = fmaxf(fmaf(x.x, sw0, fmaf(x.y, sw1, sb0)), 0.f);
            h.y = fmaxf(fmaf(x.x, sw2, fmaf(x.y, sw3, sb1)), 0.f);
        }
        *(float2*)(G + gsw(rowb + r, c0)) = h;
    }
    pass_lds(acc, G, rowb, Wcvt + (size_t)1 * MATSZ, fr, fq);

    float bi[8], bs[8];
#pragma unroll
    for (int n = 0; n < 8; ++n) { bi[n] = inb2[n * 16 + fr]; bs[n] = segb2[n * 16 + fr]; }
#pragma unroll
    for (int m = 0; m < 2; ++m)
#pragma unroll
        for (int j = 0; j < 4; ++j) {
            int row = rbase + m * 16 + fq * 4 + j;
            if (row < N) {
#pragma unroll
                for (int n = 0; n < 8; ++n)
                    Fout[(size_t)row * D + n * 16 + fr] =
                        fmaxf(acc[m][n][j] + bi[n] + bs[n], 0.f);
            }
        }
}

// ---------------------------------------------------------------------------
// Fused meta: out = relu([F, embed[mark]]@W1 + b1)@W2 + b2
// ---------------------------------------------------------------------------
__global__ __launch_bounds__(256) void meta_fused_kernel(
    const float* __restrict__ F, const int* __restrict__ mark,
    const float* __restrict__ embed, const float* __restrict__ mb1,
    const float* __restrict__ mb2, const unsigned short* __restrict__ Wcvt,
    float* __restrict__ out, int N) {
    __shared__ float G[128 * 128];
    int t = threadIdx.x, wave = t >> 6, lane = t & 63;
    int fr = lane & 15, fq = lane >> 4;
    int rbase = blockIdx.x * 128 + wave * 32;
    int rowb = wave * 32;
    int c0 = lane * 2;

    f32x4 acc[2][8];
    zero_acc(acc);
    pass_glb(acc, F, rbase, N, Wcvt + (size_t)54 * MATSZ, fr, fq);

    for (int r = 0; r < 32; ++r) {
        int u = rbase + r;
        float2 y = {0.f, 0.f};
        if (u < N) {
            int idx = mark[u];
            y = *(const float2*)&embed[(size_t)idx * D + c0];
        }
        *(float2*)(G + gsw(rowb + r, c0)) = y;
    }
    pass_lds(acc, G, rowb, Wcvt + (size_t)55 * MATSZ, fr, fq);

    float b1v[8], b2v[8];
#pragma unroll
    for (int n = 0; n < 8; ++n) { b1v[n] = mb1[n * 16 + fr]; b2v[n] = mb2[n * 16 + fr]; }
#pragma unroll
    for (int m = 0; m < 2; ++m)
#pragma unroll
        for (int n = 0; n < 8; ++n)
#pragma unroll
            for (int j = 0; j < 4; ++j)
                acc[m][n][j] = fmaxf(acc[m][n][j] + b1v[n], 0.f);

    store_lds_C(acc, G, rowb, fr, fq);
    zero_acc(acc);
    pass_lds(acc, G, rowb, Wcvt + (size_t)56 * MATSZ, fr, fq);
#pragma unroll
    for (int m = 0; m < 2; ++m)
#pragma unroll
        for (int j = 0; j < 4; ++j) {
            int row = rbase + m * 16 + fq * 4 + j;
            if (row < N) {
#pragma unroll
                for (int n = 0; n < 8; ++n)
                    out[(size_t)row * D + n * 16 + fr] = acc[m][n][j] + b2v[n];
            }
        }
}

// ---------------------------------------------------------------------------
// weight pre-conversion (unchanged, proven)
// ---------------------------------------------------------------------------
__global__ __launch_bounds__(256) void wcvt_kernel(CvtTab tab,
                                                   unsigned short* dst) {
    int bid = blockIdx.x;
    int mat = bid >> 4;
    if (mat >= NMAT) return;
    int e = (bid & 15) * 1024 + threadIdx.x * 4;
    int o = e >> 7, k = e & 127;
    const float* s = tab.src[mat];
    int ldw = tab.ldw[mat];
    float4 v = *(const float4*)&s[(size_t)o * ldw + k];
    ushort4 h, l;
    h.x = f2bf(v.x); l.x = f2bf(v.x - bf2f(h.x));
    h.y = f2bf(v.y); l.y = f2bf(v.y - bf2f(h.y));
    h.z = f2bf(v.z); l.z = f2bf(v.z - bf2f(h.z));
    h.w = f2bf(v.w); l.w = f2bf(v.w - bf2f(h.w));
    *(ushort4*)&dst[(size_t)mat * MATSZ + e] = h;
    *(ushort4*)&dst[(size_t)mat * MATSZ + 16384 + e] = l;
}

// ---------------------------------------------------------------------------
// CSR build (unchanged, proven)
// ---------------------------------------------------------------------------
__global__ void csr_hist_kernel(const int* __restrict__ edge_u, int* deg,
                                int N, int E) {
    int gid = blockIdx.x * blockDim.x + threadIdx.x;
    if (gid >= NT * E) return;
    int t = gid / E;
    int u = edge_u[gid];
    atomicAdd(&deg[(size_t)t * N + u], 1);
}

__global__ __launch_bounds__(256) void csr_chunksum_kernel(
    const int* __restrict__ deg, int* csum, int N, int nch) {
    int b = blockIdx.x;
    int t = b / nch, ch = b % nch;
    int tid = threadIdx.x;
    const int* dg = deg + (size_t)t * N;
    int base = ch * SCH + tid * 4;
    int s = 0;
#pragma unroll
    for (int j = 0; j < 4; ++j) {
        int idx = base + j;
        if (idx < N) s += dg[idx];
    }
#pragma unroll
    for (int off = 32; off; off >>= 1) s += __shfl_down(s, off);
    __shared__ int wsum[4];
    if ((tid & 63) == 0) wsum[tid >> 6] = s;
    __syncthreads();
    if (tid == 0) csum[b] = wsum[0] + wsum[1] + wsum[2] + wsum[3];
}

__global__ void csr_chunkscan_kernel(int* csum, int* rowptr, int N, int nch) {
    int t = threadIdx.x;
    if (t >= NT) return;
    int run = 0;
    for (int i = 0; i < nch; ++i) {
        int v = csum[t * nch + i];
        csum[t * nch + i] = run;
        run += v;
    }
    rowptr[(size_t)t * (N + 1) + N] = run;
}

__global__ __launch_bounds__(256) void csr_blockscan_kernel(
    const int* __restrict__ deg, const int* __restrict__ csum, int* rowptr,
    int* cur, int N, int nch) {
    int b = blockIdx.x;
    int t = b / nch, ch = b % nch;
    int tid = threadIdx.x;
    const int* dg = deg + (size_t)t * N;
    int base = ch * SCH + tid * 4;
    int d[4];
    int s = 0;
#pragma unroll
    for (int j = 0; j < 4; ++j) {
        int idx = base + j;
        d[j] = (idx < N) ? dg[idx] : 0;
        s += d[j];
    }
    __shared__ int ps[256];
    ps[tid] = s;
    __syncthreads();
    for (int off = 1; off < 256; off <<= 1) {
        int v = (tid >= off) ? ps[tid - off] : 0;
        __syncthreads();
        ps[tid] += v;
        __syncthreads();
    }
    int excl = (tid ? ps[tid - 1] : 0) + csum[b];
    size_t rb = (size_t)t * (N + 1);
#pragma unroll
    for (int j = 0; j < 4; ++j) {
        int idx = base + j;
        if (idx < N) {
            rowptr[rb + idx] = excl;
            cur[rb + idx] = excl;
            excl += d[j];
        }
    }
}

__global__ void csr_fill_kernel(const int* __restrict__ edge_u,
                                const int* __restrict__ edge_v, int* cur,
                                int* col, int N, int E) {
    int gid = blockIdx.x * blockDim.x + threadIdx.x;
    if (gid >= NT * E) return;
    int t = gid / E;
    int u = edge_u[gid];
    int v = edge_v[gid];
    int pos = atomicAdd(&cur[(size_t)t * (N + 1) + u], 1);
    col[(size_t)t * E + pos] = v;
}

// ---------------------------------------------------------------------------
extern "C" void kernel_launch(void* const* d_in, const int* in_sizes, int n_in,
                              void* d_out, int out_size, void* d_ws,
                              size_t ws_size, hipStream_t stream) {
    const float* ctrs = (const float*)d_in[0];
    const float* feats = (const float*)d_in[1];
    const float* in_W1 = (const float*)d_in[2];
    const float* in_b1 = (const float*)d_in[3];
    const float* in_W2 = (const float*)d_in[4];
    const float* in_b2 = (const float*)d_in[5];
    const float* seg_W1 = (const float*)d_in[6];
    const float* seg_b1 = (const float*)d_in[7];
    const float* seg_W2 = (const float*)d_in[8];
    const float* seg_b2 = (const float*)d_in[9];
    const float* embed = (const float*)d_in[10];
    const float* meta_W1 = (const float*)d_in[11];
    const float* meta_b1 = (const float*)d_in[12];
    const float* meta_W2 = (const float*)d_in[13];
    const float* meta_b2 = (const float*)d_in[14];
    const float* ctr_W = (const float*)d_in[15];
    const float* edge_W = (const float*)d_in[16];
    const float* norm_g = (const float*)d_in[17];
    const float* norm_b = (const float*)d_in[18];
    const float* ctr2_W1 = (const float*)d_in[19];
    const float* ctr2_b1 = (const float*)d_in[20];
    const float* ctr2_W2 = (const float*)d_in[21];
    const float* ctr2_b2 = (const float*)d_in[22];
    const int* mark_type = (const int*)d_in[23];
    const int* edge_u = (const int*)d_in[24];
    const int* edge_v = (const int*)d_in[25];

    const int N = in_sizes[0] / 2;
    const int E = in_sizes[24] / NT;
    const size_t ND = (size_t)N * D;
    const int nch = (N + SCH - 1) / SCH;

    // ws layout: [Wcvt 3.7MB | FA 77MB | FB 77MB | rowptr 6MB | col 6MB]
    unsigned short* Wcvt = (unsigned short*)d_ws;
    size_t wcB = ((size_t)NMAT * MATSZ * sizeof(unsigned short) + 255) & ~(size_t)255;
    float* FA = (float*)((char*)d_ws + wcB);
    float* FB = FA + ND;
    int* rowptr = (int*)(FB + ND);
    int* col = rowptr + (size_t)NT * (N + 1);

    // weight conversion table
    CvtTab tab;
    tab.src[0] = in_W2;  tab.ldw[0] = D;
    tab.src[1] = seg_W2; tab.ldw[1] = D;
    for (int i = 0; i < NL; ++i) { tab.src[2 + i] = ctr2_W1 + (size_t)i * D * D; tab.ldw[2 + i] = D; }
    for (int i = 0; i < NL; ++i) { tab.src[6 + i] = ctr2_W2 + (size_t)i * D * D; tab.ldw[6 + i] = D; }
    for (int i = 0; i < NL; ++i) {
        for (int t = 0; t < NT; ++t) {
            int id = 10 + i * 11 + t;
            tab.src[id] = edge_W + ((size_t)i * NT + t) * D * D;
            tab.ldw[id] = D;
        }
        tab.src[10 + i * 11 + 10] = ctr_W + (size_t)i * D * D;
        tab.ldw[10 + i * 11 + 10] = D;
    }
    tab.src[54] = meta_W1;     tab.ldw[54] = 2 * D;
    tab.src[55] = meta_W1 + D; tab.ldw[55] = 2 * D;
    tab.src[56] = meta_W2;     tab.ldw[56] = D;
    wcvt_kernel<<<NMAT * 16, 256, 0, stream>>>(tab, Wcvt);

    dim3 blk(256);
    dim3 gTE(((size_t)NT * E + 255) / 256);
    int nblk = (N + 127) / 128;

    // CSR build (d_out is free scratch until the meta kernel)
    {
        int* deg = (int*)d_out;
        int* cur = deg + (size_t)NT * N;
        int* csum = cur + (size_t)NT * (N + 1);
        hipMemsetAsync(deg, 0, (size_t)NT * N * sizeof(int), stream);
        csr_hist_kernel<<<gTE, blk, 0, stream>>>(edge_u, deg, N, E);
        csr_chunksum_kernel<<<NT * nch, blk, 0, stream>>>(deg, csum, N, nch);
        csr_chunkscan_kernel<<<1, 64, 0, stream>>>(csum, rowptr, N, nch);
        csr_blockscan_kernel<<<NT * nch, blk, 0, stream>>>(deg, csum, rowptr, cur, N, nch);
        csr_fill_kernel<<<gTE, blk, 0, stream>>>(edge_u, edge_v, cur, col, N, E);
    }

    // input stage -> FA
    input_fused_kernel<<<nblk, blk, 0, stream>>>(ctrs, feats, in_W1, in_b1,
                                                 seg_W1, seg_b1, in_b2, seg_b2,
                                                 Wcvt, FA, N);

    // 4 fused layers, ping-pong FA <-> FB
    float* Fi = FA;
    float* Fo = FB;
    for (int i = 0; i < NL; ++i) {
        layer_fused_kernel<<<nblk, blk, 0, stream>>>(
            Fi, Fo, Wcvt, i, rowptr, col, norm_g + (size_t)i * D,
            norm_b + (size_t)i * D, ctr2_b1 + (size_t)i * D,
            ctr2_b2 + (size_t)i * D, N, E);
        float* tmp = Fi; Fi = Fo; Fo = tmp;
    }

    // meta stage -> d_out  (Fi holds the final features)
    meta_fused_kernel<<<nblk, blk, 0, stream>>>(Fi, mark_type, embed, meta_b1,
                                                meta_b2, Wcvt, (float*)d_out, N);
}

// Round 7
// 6703.078 us; speedup vs baseline: 1.0222x; 1.0222x over previous
//
#include <hip/hip_runtime.h>

#define D 128
#define NT 10    // edge types
#define NL 4     // layers
#define SCH 1024 // nodes per scan chunk
#define NMAT 57
#define MATSZ 32768  // shorts per converted matrix (hi 16384 + lo 16384)

typedef __attribute__((ext_vector_type(8))) short bf16x8;
typedef __attribute__((ext_vector_type(4))) float f32x4;

struct CvtTab { const float* src[NMAT]; int ldw[NMAT]; };

__device__ inline unsigned short f2bf(float x) {
    union { float f; unsigned u; } v; v.f = x;
    unsigned r = v.u + 0x7FFFu + ((v.u >> 16) & 1u);
    return (unsigned short)(r >> 16);
}
__device__ inline float bf2f(unsigned short h) {
    union { unsigned u; float f; } v; v.u = ((unsigned)h) << 16;
    return v.f;
}
__device__ inline void cvt8(const float4& v0, const float4& v1, bf16x8& h,
                            bf16x8& l) {
    float f[8] = {v0.x, v0.y, v0.z, v0.w, v1.x, v1.y, v1.z, v1.w};
#pragma unroll
    for (int j = 0; j < 8; ++j) {
        unsigned short hh = f2bf(f[j]);
        h[j] = (short)hh;
        l[j] = (short)f2bf(f[j] - bf2f(hh));
    }
}
__device__ inline f32x4 MF(bf16x8 a, bf16x8 b, f32x4 c) {
    return __builtin_amdgcn_mfma_f32_16x16x32_bf16(a, b, c, 0, 0, 0);
}

// XOR-granule swizzle for the 128x128 fp32 LDS tile (64 KB)
__device__ inline int gsw(int row, int c) {
    return (row << 7) + (((((c >> 2) ^ ((row & 7) << 2)) & 31) << 2) | (c & 3));
}

// MFMA pass, A = 32 fp32 rows [rowb..rowb+32) of the swizzled LDS tile
__device__ inline void pass_lds(f32x4 (&acc)[2][8], const float* G, int rowb,
                                const unsigned short* Wm, int fr, int fq) {
#pragma unroll
    for (int kc = 0; kc < 4; ++kc) {
        int ko = kc * 32 + fq * 8;
        bf16x8 ah[2], al[2];
#pragma unroll
        for (int m = 0; m < 2; ++m) {
            int row = rowb + m * 16 + fr;
            float4 v0 = *(const float4*)(G + gsw(row, ko));
            float4 v1 = *(const float4*)(G + gsw(row, ko + 4));
            cvt8(v0, v1, ah[m], al[m]);
        }
#pragma unroll
        for (int n = 0; n < 8; ++n) {
            const unsigned short* wp = Wm + (size_t)(n * 16 + fr) * D + ko;
            bf16x8 wh = *(const bf16x8*)wp;
            bf16x8 wl = *(const bf16x8*)(wp + 16384);
#pragma unroll
            for (int m = 0; m < 2; ++m) {
                acc[m][n] = MF(ah[m], wh, acc[m][n]);
                acc[m][n] = MF(ah[m], wl, acc[m][n]);
                acc[m][n] = MF(al[m], wh, acc[m][n]);
            }
        }
    }
}

// MFMA pass, A = fp32 rows straight from global (row-guarded)
__device__ inline void pass_glb(f32x4 (&acc)[2][8], const float* A, int rbase,
                                int N, const unsigned short* Wm, int fr,
                                int fq) {
    int r0 = rbase + fr, r1 = rbase + 16 + fr;
    const float* a0 = A + (size_t)r0 * D;
    const float* a1 = A + (size_t)r1 * D;
    bool ok0 = r0 < N, ok1 = r1 < N;
#pragma unroll
    for (int kc = 0; kc < 4; ++kc) {
        int ko = kc * 32 + fq * 8;
        bf16x8 ah[2], al[2];
        float4 v0 = {0, 0, 0, 0}, v1 = {0, 0, 0, 0};
        if (ok0) { v0 = *(const float4*)(a0 + ko); v1 = *(const float4*)(a0 + ko + 4); }
        cvt8(v0, v1, ah[0], al[0]);
        float4 u0 = {0, 0, 0, 0}, u1 = {0, 0, 0, 0};
        if (ok1) { u0 = *(const float4*)(a1 + ko); u1 = *(const float4*)(a1 + ko + 4); }
        cvt8(u0, u1, ah[1], al[1]);
#pragma unroll
        for (int n = 0; n < 8; ++n) {
            const unsigned short* wp = Wm + (size_t)(n * 16 + fr) * D + ko;
            bf16x8 wh = *(const bf16x8*)wp;
            bf16x8 wl = *(const bf16x8*)(wp + 16384);
#pragma unroll
            for (int m = 0; m < 2; ++m) {
                acc[m][n] = MF(ah[m], wh, acc[m][n]);
                acc[m][n] = MF(ah[m], wl, acc[m][n]);
                acc[m][n] = MF(al[m], wh, acc[m][n]);
            }
        }
    }
}

__device__ inline void zero_acc(f32x4 (&acc)[2][8]) {
#pragma unroll
    for (int m = 0; m < 2; ++m)
#pragma unroll
        for (int n = 0; n < 8; ++n) acc[m][n] = (f32x4){0.f, 0.f, 0.f, 0.f};
}

// write acc (C layout: row=m*16+fq*4+j, col=n*16+fr) into the LDS tile
__device__ inline void store_lds_C(const f32x4 (&acc)[2][8], float* G,
                                   int rowb, int fr, int fq) {
#pragma unroll
    for (int m = 0; m < 2; ++m)
#pragma unroll
        for (int j = 0; j < 4; ++j) {
            int row = rowb + m * 16 + fq * 4 + j;
#pragma unroll
            for (int n = 0; n < 8; ++n) G[gsw(row, n * 16 + fr)] = acc[m][n][j];
        }
}

// ---------------------------------------------------------------------------
// Fused layer: temp = F@Wc + edge-aggregates; GroupNorm+relu; MLP; residual.
// Edge-centric gather: prefetch (v,u) pairs into registers, pipelined row
// reads of Fin, LDS fp32 atomic accumulation into wave-private S region.
// ---------------------------------------------------------------------------
__global__ __launch_bounds__(256) void layer_fused_kernel(
    const float* __restrict__ Fin, float* __restrict__ Fout,
    const unsigned short* __restrict__ Wcvt, int li,
    const int* __restrict__ rowptr, const int* __restrict__ col,
    const int* __restrict__ rowid, const float* __restrict__ ng,
    const float* __restrict__ nb, const float* __restrict__ mb1,
    const float* __restrict__ mb2, int N, int E) {
    __shared__ float G[128 * 128];
    int t = threadIdx.x, wave = t >> 6, lane = t & 63;
    int fr = lane & 15, fq = lane >> 4;
    int rbase = blockIdx.x * 128 + wave * 32;
    int rowb = wave * 32;

    f32x4 acc[2][8];
    zero_acc(acc);

    const unsigned short* WL = Wcvt + (size_t)(10 + li * 11) * MATSZ;
    // ctr term: A = Fin rows streamed from global
    pass_glb(acc, Fin, rbase, N, WL + (size_t)10 * MATSZ, fr, fq);

    // hoisted beg/end for all 10 types: lane 2t -> rp_t[rbase], 2t+1 -> rp_t[rbase+32]
    int be = 0;
    {
        int tsel = lane >> 1, which = lane & 1;
        if (tsel < NT)
            be = rowptr[(size_t)tsel * (N + 1) + min(rbase + which * 32, N)];
    }

    for (int tt = 0; tt < NT; ++tt) {
        const int* cj = col + (size_t)tt * E;
        const int* rw = rowid + (size_t)tt * E;
        // zero wave's S region (flat 4096 floats)
        float4 z4 = {0.f, 0.f, 0.f, 0.f};
#pragma unroll
        for (int i = 0; i < 16; ++i)
            *(float4*)&G[rowb * 128 + i * 256 + lane * 4] = z4;

        int beg = __builtin_amdgcn_readlane(be, 2 * tt);
        int end = __builtin_amdgcn_readlane(be, 2 * tt + 1);
        int tot = end - beg;
        // prefetch up to 128 (v,u) pairs into lane registers
        int idx0 = 0, idx1 = 0, u0 = 0, u1 = 0;
        if (lane < tot) { idx0 = cj[beg + lane]; u0 = rw[beg + lane]; }
        if (64 + lane < tot) { idx1 = cj[beg + 64 + lane]; u1 = rw[beg + 64 + lane]; }
        int klim = min(tot, 128);
#pragma unroll 4
        for (int k = 0; k < klim; ++k) {
            int v, u;
            if (k < 64) {
                v = __builtin_amdgcn_readlane(idx0, k);
                u = __builtin_amdgcn_readlane(u0, k);
            } else {
                v = __builtin_amdgcn_readlane(idx1, k - 64);
                u = __builtin_amdgcn_readlane(u1, k - 64);
            }
            float2 y = *(const float2*)&Fin[(size_t)v * D + 2 * lane];
            int a = gsw(rowb + (u - rbase), 2 * lane);
            atomicAdd(&G[a], y.x);
            atomicAdd(&G[a + 1], y.y);
        }
        for (int k = 128; k < tot; ++k) {  // overflow path (deg sum > 128): rare
            int v = cj[beg + k], u = rw[beg + k];
            float2 y = *(const float2*)&Fin[(size_t)v * D + 2 * lane];
            int a = gsw(rowb + (u - rbase), 2 * lane);
            atomicAdd(&G[a], y.x);
            atomicAdd(&G[a + 1], y.y);
        }
        pass_lds(acc, G, rowb, WL + (size_t)tt * MATSZ, fr, fq);
    }

    // GroupNorm(1,D) + affine + relu, fully in-register
    float gv[8], bv[8];
#pragma unroll
    for (int n = 0; n < 8; ++n) { gv[n] = ng[n * 16 + fr]; bv[n] = nb[n * 16 + fr]; }
#pragma unroll
    for (int m = 0; m < 2; ++m)
#pragma unroll
        for (int j = 0; j < 4; ++j) {
            float s = 0.f, q = 0.f;
#pragma unroll
            for (int n = 0; n < 8; ++n) { float x = acc[m][n][j]; s += x; q += x * x; }
#pragma unroll
            for (int o = 1; o <= 8; o <<= 1) { s += __shfl_xor(s, o); q += __shfl_xor(q, o); }
            float mu = s * (1.f / 128.f);
            float var = q * (1.f / 128.f) - mu * mu;
            float rs = rsqrtf(var + 1e-5f);
#pragma unroll
            for (int n = 0; n < 8; ++n)
                acc[m][n][j] = fmaxf(fmaf((acc[m][n][j] - mu) * rs, gv[n], bv[n]), 0.f);
        }

    // MLP1: H = relu(T@W1 + b1)   (T bounced through LDS, wave-local)
    store_lds_C(acc, G, rowb, fr, fq);
    zero_acc(acc);
    pass_lds(acc, G, rowb, Wcvt + (size_t)(2 + li) * MATSZ, fr, fq);
    float b1v[8], b2v[8];
#pragma unroll
    for (int n = 0; n < 8; ++n) { b1v[n] = mb1[n * 16 + fr]; b2v[n] = mb2[n * 16 + fr]; }
#pragma unroll
    for (int m = 0; m < 2; ++m)
#pragma unroll
        for (int n = 0; n < 8; ++n)
#pragma unroll
            for (int j = 0; j < 4; ++j)
                acc[m][n][j] = fmaxf(acc[m][n][j] + b1v[n], 0.f);

    // MLP2 + residual + relu
    store_lds_C(acc, G, rowb, fr, fq);
    zero_acc(acc);
    pass_lds(acc, G, rowb, Wcvt + (size_t)(6 + li) * MATSZ, fr, fq);
#pragma unroll
    for (int m = 0; m < 2; ++m)
#pragma unroll
        for (int j = 0; j < 4; ++j) {
            int row = rbase + m * 16 + fq * 4 + j;
            if (row < N) {
#pragma unroll
                for (int n = 0; n < 8; ++n) {
                    int c = n * 16 + fr;
                    float r = acc[m][n][j] + b2v[n] + Fin[(size_t)row * D + c];
                    Fout[(size_t)row * D + c] = fmaxf(r, 0.f);
                }
            }
        }
}

// ---------------------------------------------------------------------------
// Fused input: F = relu(h1@W2_in + b_in2 + h2@W2_seg + b_seg2)
// ---------------------------------------------------------------------------
__global__ __launch_bounds__(256) void input_fused_kernel(
    const float* __restrict__ ctrs, const float* __restrict__ feats,
    const float* __restrict__ inW1, const float* __restrict__ inb1,
    const float* __restrict__ segW1, const float* __restrict__ segb1,
    const float* __restrict__ inb2, const float* __restrict__ segb2,
    const unsigned short* __restrict__ Wcvt, float* __restrict__ Fout, int N) {
    __shared__ float G[128 * 128];
    int t = threadIdx.x, wave = t >> 6, lane = t & 63;
    int fr = lane & 15, fq = lane >> 4;
    int rbase = blockIdx.x * 128 + wave * 32;
    int rowb = wave * 32;
    int c0 = lane * 2;

    float iw0 = inW1[2 * c0], iw1 = inW1[2 * c0 + 1], iw2 = inW1[2 * c0 + 2],
          iw3 = inW1[2 * c0 + 3];
    float ib0 = inb1[c0], ib1 = inb1[c0 + 1];
    float sw0 = segW1[2 * c0], sw1 = segW1[2 * c0 + 1], sw2 = segW1[2 * c0 + 2],
          sw3 = segW1[2 * c0 + 3];
    float sb0 = segb1[c0], sb1 = segb1[c0 + 1];

    f32x4 acc[2][8];
    zero_acc(acc);

    for (int r = 0; r < 32; ++r) {
        int u = rbase + r;
        float2 h = {0.f, 0.f};
        if (u < N) {
            float2 x = *(const float2*)&ctrs[2 * (size_t)u];
            h.x = fmaxf(fmaf(x.x, iw0, fmaf(x.y, iw1, ib0)), 0.f);
            h.y = fmaxf(fmaf(x.x, iw2, fmaf(x.y, iw3, ib1)), 0.f);
        }
        *(float2*)(G + gsw(rowb + r, c0)) = h;
    }
    pass_lds(acc, G, rowb, Wcvt + (size_t)0 * MATSZ, fr, fq);

    for (int r = 0; r < 32; ++r) {
        int u = rbase + r;
        float2 h = {0.f, 0.f};
        if (u < N) {
            float2 x = *(const float2*)&feats[2 * (size_t)u];
            h.x = fmaxf(fmaf(x.x, sw0, fmaf(x.y, sw1, sb0)), 0.f);
            h.y = fmaxf(fmaf(x.x, sw2, fmaf(x.y, sw3, sb1)), 0.f);
        }
        *(float2*)(G + gsw(rowb + r, c0)) = h;
    }
    pass_lds(acc, G, rowb, Wcvt + (size_t)1 * MATSZ, fr, fq);

    float bi[8], bs[8];
#pragma unroll
    for (int n = 0; n < 8; ++n) { bi[n] = inb2[n * 16 + fr]; bs[n] = segb2[n * 16 + fr]; }
#pragma unroll
    for (int m = 0; m < 2; ++m)
#pragma unroll
        for (int j = 0; j < 4; ++j) {
            int row = rbase + m * 16 + fq * 4 + j;
            if (row < N) {
#pragma unroll
                for (int n = 0; n < 8; ++n)
                    Fout[(size_t)row * D + n * 16 + fr] =
                        fmaxf(acc[m][n][j] + bi[n] + bs[n], 0.f);
            }
        }
}

// ---------------------------------------------------------------------------
// Fused meta: out = relu([F, embed[mark]]@W1 + b1)@W2 + b2
// ---------------------------------------------------------------------------
__global__ __launch_bounds__(256) void meta_fused_kernel(
    const float* __restrict__ F, const int* __restrict__ mark,
    const float* __restrict__ embed, const float* __restrict__ mb1,
    const float* __restrict__ mb2, const unsigned short* __restrict__ Wcvt,
    float* __restrict__ out, int N) {
    __shared__ float G[128 * 128];
    int t = threadIdx.x, wave = t >> 6, lane = t & 63;
    int fr = lane & 15, fq = lane >> 4;
    int rbase = blockIdx.x * 128 + wave * 32;
    int rowb = wave * 32;
    int c0 = lane * 2;

    f32x4 acc[2][8];
    zero_acc(acc);
    pass_glb(acc, F, rbase, N, Wcvt + (size_t)54 * MATSZ, fr, fq);

    for (int r = 0; r < 32; ++r) {
        int u = rbase + r;
        float2 y = {0.f, 0.f};
        if (u < N) {
            int idx = mark[u];
            y = *(const float2*)&embed[(size_t)idx * D + c0];
        }
        *(float2*)(G + gsw(rowb + r, c0)) = y;
    }
    pass_lds(acc, G, rowb, Wcvt + (size_t)55 * MATSZ, fr, fq);

    float b1v[8], b2v[8];
#pragma unroll
    for (int n = 0; n < 8; ++n) { b1v[n] = mb1[n * 16 + fr]; b2v[n] = mb2[n * 16 + fr]; }
#pragma unroll
    for (int m = 0; m < 2; ++m)
#pragma unroll
        for (int n = 0; n < 8; ++n)
#pragma unroll
            for (int j = 0; j < 4; ++j)
                acc[m][n][j] = fmaxf(acc[m][n][j] + b1v[n], 0.f);

    store_lds_C(acc, G, rowb, fr, fq);
    zero_acc(acc);
    pass_lds(acc, G, rowb, Wcvt + (size_t)56 * MATSZ, fr, fq);
#pragma unroll
    for (int m = 0; m < 2; ++m)
#pragma unroll
        for (int j = 0; j < 4; ++j) {
            int row = rbase + m * 16 + fq * 4 + j;
            if (row < N) {
#pragma unroll
                for (int n = 0; n < 8; ++n)
                    out[(size_t)row * D + n * 16 + fr] = acc[m][n][j] + b2v[n];
            }
        }
}

// ---------------------------------------------------------------------------
// weight pre-conversion (unchanged, proven)
// ---------------------------------------------------------------------------
__global__ __launch_bounds__(256) void wcvt_kernel(CvtTab tab,
                                                   unsigned short* dst) {
    int bid = blockIdx.x;
    int mat = bid >> 4;
    if (mat >= NMAT) return;
    int e = (bid & 15) * 1024 + threadIdx.x * 4;
    int o = e >> 7, k = e & 127;
    const float* s = tab.src[mat];
    int ldw = tab.ldw[mat];
    float4 v = *(const float4*)&s[(size_t)o * ldw + k];
    ushort4 h, l;
    h.x = f2bf(v.x); l.x = f2bf(v.x - bf2f(h.x));
    h.y = f2bf(v.y); l.y = f2bf(v.y - bf2f(h.y));
    h.z = f2bf(v.z); l.z = f2bf(v.z - bf2f(h.z));
    h.w = f2bf(v.w); l.w = f2bf(v.w - bf2f(h.w));
    *(ushort4*)&dst[(size_t)mat * MATSZ + e] = h;
    *(ushort4*)&dst[(size_t)mat * MATSZ + 16384 + e] = l;
}

// ---------------------------------------------------------------------------
// CSR build (csr_fill now also writes rowid)
// ---------------------------------------------------------------------------
__global__ void csr_hist_kernel(const int* __restrict__ edge_u, int* deg,
                                int N, int E) {
    int gid = blockIdx.x * blockDim.x + threadIdx.x;
    if (gid >= NT * E) return;
    int t = gid / E;
    int u = edge_u[gid];
    atomicAdd(&deg[(size_t)t * N + u], 1);
}

__global__ __launch_bounds__(256) void csr_chunksum_kernel(
    const int* __restrict__ deg, int* csum, int N, int nch) {
    int b = blockIdx.x;
    int t = b / nch, ch = b % nch;
    int tid = threadIdx.x;
    const int* dg = deg + (size_t)t * N;
    int base = ch * SCH + tid * 4;
    int s = 0;
#pragma unroll
    for (int j = 0; j < 4; ++j) {
        int idx = base + j;
        if (idx < N) s += dg[idx];
    }
#pragma unroll
    for (int off = 32; off; off >>= 1) s += __shfl_down(s, off);
    __shared__ int wsum[4];
    if ((tid & 63) == 0) wsum[tid >> 6] = s;
    __syncthreads();
    if (tid == 0) csum[b] = wsum[0] + wsum[1] + wsum[2] + wsum[3];
}

__global__ void csr_chunkscan_kernel(int* csum, int* rowptr, int N, int nch) {
    int t = threadIdx.x;
    if (t >= NT) return;
    int run = 0;
    for (int i = 0; i < nch; ++i) {
        int v = csum[t * nch + i];
        csum[t * nch + i] = run;
        run += v;
    }
    rowptr[(size_t)t * (N + 1) + N] = run;
}

__global__ __launch_bounds__(256) void csr_blockscan_kernel(
    const int* __restrict__ deg, const int* __restrict__ csum, int* rowptr,
    int* cur, int N, int nch) {
    int b = blockIdx.x;
    int t = b / nch, ch = b % nch;
    int tid = threadIdx.x;
    const int* dg = deg + (size_t)t * N;
    int base = ch * SCH + tid * 4;
    int d[4];
    int s = 0;
#pragma unroll
    for (int j = 0; j < 4; ++j) {
        int idx = base + j;
        d[j] = (idx < N) ? dg[idx] : 0;
        s += d[j];
    }
    __shared__ int ps[256];
    ps[tid] = s;
    __syncthreads();
    for (int off = 1; off < 256; off <<= 1) {
        int v = (tid >= off) ? ps[tid - off] : 0;
        __syncthreads();
        ps[tid] += v;
        __syncthreads();
    }
    int excl = (tid ? ps[tid - 1] : 0) + csum[b];
    size_t rb = (size_t)t * (N + 1);
#pragma unroll
    for (int j = 0; j < 4; ++j) {
        int idx = base + j;
        if (idx < N) {
            rowptr[rb + idx] = excl;
            cur[rb + idx] = excl;
            excl += d[j];
        }
    }
}

__global__ void csr_fill_kernel(const int* __restrict__ edge_u,
                                const int* __restrict__ edge_v, int* cur,
                                int* col, int* rowid, int N, int E) {
    int gid = blockIdx.x * blockDim.x + threadIdx.x;
    if (gid >= NT * E) return;
    int t = gid / E;
    int u = edge_u[gid];
    int v = edge_v[gid];
    int pos = atomicAdd(&cur[(size_t)t * (N + 1) + u], 1);
    col[(size_t)t * E + pos] = v;
    rowid[(size_t)t * E + pos] = u;
}

// ---------------------------------------------------------------------------
extern "C" void kernel_launch(void* const* d_in, const int* in_sizes, int n_in,
                              void* d_out, int out_size, void* d_ws,
                              size_t ws_size, hipStream_t stream) {
    const float* ctrs = (const float*)d_in[0];
    const float* feats = (const float*)d_in[1];
    const float* in_W1 = (const float*)d_in[2];
    const float* in_b1 = (const float*)d_in[3];
    const float* in_W2 = (const float*)d_in[4];
    const float* in_b2 = (const float*)d_in[5];
    const float* seg_W1 = (const float*)d_in[6];
    const float* seg_b1 = (const float*)d_in[7];
    const float* seg_W2 = (const float*)d_in[8];
    const float* seg_b2 = (const float*)d_in[9];
    const float* embed = (const float*)d_in[10];
    const float* meta_W1 = (const float*)d_in[11];
    const float* meta_b1 = (const float*)d_in[12];
    const float* meta_W2 = (const float*)d_in[13];
    const float* meta_b2 = (const float*)d_in[14];
    const float* ctr_W = (const float*)d_in[15];
    const float* edge_W = (const float*)d_in[16];
    const float* norm_g = (const float*)d_in[17];
    const float* norm_b = (const float*)d_in[18];
    const float* ctr2_W1 = (const float*)d_in[19];
    const float* ctr2_b1 = (const float*)d_in[20];
    const float* ctr2_W2 = (const float*)d_in[21];
    const float* ctr2_b2 = (const float*)d_in[22];
    const int* mark_type = (const int*)d_in[23];
    const int* edge_u = (const int*)d_in[24];
    const int* edge_v = (const int*)d_in[25];

    const int N = in_sizes[0] / 2;
    const int E = in_sizes[24] / NT;
    const size_t ND = (size_t)N * D;
    const int nch = (N + SCH - 1) / SCH;

    // ws layout: [Wcvt 3.7MB | FA 77MB | FB 77MB | rowptr 6MB | col 6MB]
    unsigned short* Wcvt = (unsigned short*)d_ws;
    size_t wcB = ((size_t)NMAT * MATSZ * sizeof(unsigned short) + 255) & ~(size_t)255;
    float* FA = (float*)((char*)d_ws + wcB);
    float* FB = FA + ND;
    int* rowptr = (int*)(FB + ND);
    int* col = rowptr + (size_t)NT * (N + 1);

    // d_out scratch: rowid (persists through layers) + CSR-build temps
    int* rowid = (int*)d_out;                      // NT*E
    int* deg = rowid + (size_t)NT * E;             // NT*N
    int* cur = deg + (size_t)NT * N;               // NT*(N+1)
    int* csum = cur + (size_t)NT * (N + 1);        // NT*nch

    // weight conversion table
    CvtTab tab;
    tab.src[0] = in_W2;  tab.ldw[0] = D;
    tab.src[1] = seg_W2; tab.ldw[1] = D;
    for (int i = 0; i < NL; ++i) { tab.src[2 + i] = ctr2_W1 + (size_t)i * D * D; tab.ldw[2 + i] = D; }
    for (int i = 0; i < NL; ++i) { tab.src[6 + i] = ctr2_W2 + (size_t)i * D * D; tab.ldw[6 + i] = D; }
    for (int i = 0; i < NL; ++i) {
        for (int t = 0; t < NT; ++t) {
            int id = 10 + i * 11 + t;
            tab.src[id] = edge_W + ((size_t)i * NT + t) * D * D;
            tab.ldw[id] = D;
        }
        tab.src[10 + i * 11 + 10] = ctr_W + (size_t)i * D * D;
        tab.ldw[10 + i * 11 + 10] = D;
    }
    tab.src[54] = meta_W1;     tab.ldw[54] = 2 * D;
    tab.src[55] = meta_W1 + D; tab.ldw[55] = 2 * D;
    tab.src[56] = meta_W2;     tab.ldw[56] = D;
    wcvt_kernel<<<NMAT * 16, 256, 0, stream>>>(tab, Wcvt);

    dim3 blk(256);
    dim3 gTE(((size_t)NT * E + 255) / 256);
    int nblk = (N + 127) / 128;

    // CSR build
    hipMemsetAsync(deg, 0, (size_t)NT * N * sizeof(int), stream);
    csr_hist_kernel<<<gTE, blk, 0, stream>>>(edge_u, deg, N, E);
    csr_chunksum_kernel<<<NT * nch, blk, 0, stream>>>(deg, csum, N, nch);
    csr_chunkscan_kernel<<<1, 64, 0, stream>>>(csum, rowptr, N, nch);
    csr_blockscan_kernel<<<NT * nch, blk, 0, stream>>>(deg, csum, rowptr, cur, N, nch);
    csr_fill_kernel<<<gTE, blk, 0, stream>>>(edge_u, edge_v, cur, col, rowid, N, E);

    // input stage -> FA
    input_fused_kernel<<<nblk, blk, 0, stream>>>(ctrs, feats, in_W1, in_b1,
                                                 seg_W1, seg_b1, in_b2, seg_b2,
                                                 Wcvt, FA, N);

    // 4 fused layers, ping-pong FA <-> FB
    float* Fi = FA;
    float* Fo = FB;
    for (int i = 0; i < NL; ++i) {
        layer_fused_kernel<<<nblk, blk, 0, stream>>>(
            Fi, Fo, Wcvt, i, rowptr, col, rowid, norm_g + (size_t)i * D,
            norm_b + (size_t)i * D, ctr2_b1 + (size_t)i * D,
            ctr2_b2 + (size_t)i * D, N, E);
        float* tmp = Fi; Fi = Fo; Fo = tmp;
    }

    // meta stage -> d_out  (rowid no longer needed)
    meta_fused_kernel<<<nblk, blk, 0, stream>>>(Fi, mark_type, embed, meta_b1,
                                                meta_b2, Wcvt, (float*)d_out, N);
}

// Round 8
// 6316.904 us; speedup vs baseline: 1.0847x; 1.0611x over previous
//
#include <hip/hip_runtime.h>

#define D 128
#define NT 10    // edge types
#define NL 4     // layers
#define SCH 1024 // nodes per scan chunk
#define NMAT 57
#define MATSZ 32768  // shorts per converted matrix (hi 16384 + lo 16384)

typedef __attribute__((ext_vector_type(8))) short bf16x8;
typedef __attribute__((ext_vector_type(4))) float f32x4;

struct CvtTab { const float* src[NMAT]; int ldw[NMAT]; };

__device__ inline unsigned short f2bf(float x) {
    union { float f; unsigned u; } v; v.f = x;
    unsigned r = v.u + 0x7FFFu + ((v.u >> 16) & 1u);
    return (unsigned short)(r >> 16);
}
__device__ inline float bf2f(unsigned short h) {
    union { unsigned u; float f; } v; v.u = ((unsigned)h) << 16;
    return v.f;
}
__device__ inline void cvt8(const float4& v0, const float4& v1, bf16x8& h,
                            bf16x8& l) {
    float f[8] = {v0.x, v0.y, v0.z, v0.w, v1.x, v1.y, v1.z, v1.w};
#pragma unroll
    for (int j = 0; j < 8; ++j) {
        unsigned short hh = f2bf(f[j]);
        h[j] = (short)hh;
        l[j] = (short)f2bf(f[j] - bf2f(hh));
    }
}
__device__ inline f32x4 MF(bf16x8 a, bf16x8 b, f32x4 c) {
    return __builtin_amdgcn_mfma_f32_16x16x32_bf16(a, b, c, 0, 0, 0);
}

// XOR-granule swizzle for the 128x128 fp32 LDS tile (64 KB)
__device__ inline int gsw(int row, int c) {
    return (row << 7) + (((((c >> 2) ^ ((row & 7) << 2)) & 31) << 2) | (c & 3));
}

// MFMA pass, A = 32 fp32 rows [rowb..rowb+32) of the swizzled LDS tile
__device__ inline void pass_lds(f32x4 (&acc)[2][8], const float* G, int rowb,
                                const unsigned short* Wm, int fr, int fq) {
#pragma unroll
    for (int kc = 0; kc < 4; ++kc) {
        int ko = kc * 32 + fq * 8;
        bf16x8 ah[2], al[2];
#pragma unroll
        for (int m = 0; m < 2; ++m) {
            int row = rowb + m * 16 + fr;
            float4 v0 = *(const float4*)(G + gsw(row, ko));
            float4 v1 = *(const float4*)(G + gsw(row, ko + 4));
            cvt8(v0, v1, ah[m], al[m]);
        }
#pragma unroll
        for (int n = 0; n < 8; ++n) {
            const unsigned short* wp = Wm + (size_t)(n * 16 + fr) * D + ko;
            bf16x8 wh = *(const bf16x8*)wp;
            bf16x8 wl = *(const bf16x8*)(wp + 16384);
#pragma unroll
            for (int m = 0; m < 2; ++m) {
                acc[m][n] = MF(ah[m], wh, acc[m][n]);
                acc[m][n] = MF(ah[m], wl, acc[m][n]);
                acc[m][n] = MF(al[m], wh, acc[m][n]);
            }
        }
    }
}

// MFMA pass, A = fp32 rows straight from global (row-guarded)
__device__ inline void pass_glb(f32x4 (&acc)[2][8], const float* A, int rbase,
                                int N, const unsigned short* Wm, int fr,
                                int fq) {
    int r0 = rbase + fr, r1 = rbase + 16 + fr;
    const float* a0 = A + (size_t)r0 * D;
    const float* a1 = A + (size_t)r1 * D;
    bool ok0 = r0 < N, ok1 = r1 < N;
#pragma unroll
    for (int kc = 0; kc < 4; ++kc) {
        int ko = kc * 32 + fq * 8;
        bf16x8 ah[2], al[2];
        float4 v0 = {0, 0, 0, 0}, v1 = {0, 0, 0, 0};
        if (ok0) { v0 = *(const float4*)(a0 + ko); v1 = *(const float4*)(a0 + ko + 4); }
        cvt8(v0, v1, ah[0], al[0]);
        float4 u0 = {0, 0, 0, 0}, u1 = {0, 0, 0, 0};
        if (ok1) { u0 = *(const float4*)(a1 + ko); u1 = *(const float4*)(a1 + ko + 4); }
        cvt8(u0, u1, ah[1], al[1]);
#pragma unroll
        for (int n = 0; n < 8; ++n) {
            const unsigned short* wp = Wm + (size_t)(n * 16 + fr) * D + ko;
            bf16x8 wh = *(const bf16x8*)wp;
            bf16x8 wl = *(const bf16x8*)(wp + 16384);
#pragma unroll
            for (int m = 0; m < 2; ++m) {
                acc[m][n] = MF(ah[m], wh, acc[m][n]);
                acc[m][n] = MF(ah[m], wl, acc[m][n]);
                acc[m][n] = MF(al[m], wh, acc[m][n]);
            }
        }
    }
}

__device__ inline void zero_acc(f32x4 (&acc)[2][8]) {
#pragma unroll
    for (int m = 0; m < 2; ++m)
#pragma unroll
        for (int n = 0; n < 8; ++n) acc[m][n] = (f32x4){0.f, 0.f, 0.f, 0.f};
}

// write acc (C layout: row=m*16+fq*4+j, col=n*16+fr) into the LDS tile
__device__ inline void store_lds_C(const f32x4 (&acc)[2][8], float* G,
                                   int rowb, int fr, int fq) {
#pragma unroll
    for (int m = 0; m < 2; ++m)
#pragma unroll
        for (int j = 0; j < 4; ++j) {
            int row = rowb + m * 16 + fq * 4 + j;
#pragma unroll
            for (int n = 0; n < 8; ++n) G[gsw(row, n * 16 + fr)] = acc[m][n][j];
        }
}

// ---------------------------------------------------------------------------
// Fused layer with two-phase batched gather (16 loads in flight per wave).
// ---------------------------------------------------------------------------
__global__ __launch_bounds__(256) void layer_fused_kernel(
    const float* __restrict__ Fin, float* __restrict__ Fout,
    const unsigned short* __restrict__ Wcvt, int li,
    const int* __restrict__ rowptr, const int* __restrict__ col,
    const int* __restrict__ rowid, const float* __restrict__ ng,
    const float* __restrict__ nb, const float* __restrict__ mb1,
    const float* __restrict__ mb2, int N, int E) {
    __shared__ float G[128 * 128];
    int t = threadIdx.x, wave = t >> 6, lane = t & 63;
    int fr = lane & 15, fq = lane >> 4;
    int rbase = blockIdx.x * 128 + wave * 32;
    int rowb = wave * 32;
    int lc = lane << 1;

    f32x4 acc[2][8];
    zero_acc(acc);

    const unsigned short* WL = Wcvt + (size_t)(10 + li * 11) * MATSZ;
    // ctr term: A = Fin rows streamed from global
    pass_glb(acc, Fin, rbase, N, WL + (size_t)10 * MATSZ, fr, fq);

    // hoisted beg/end for all 10 types: lane 2t -> rp_t[rbase], 2t+1 -> rp_t[rbase+32]
    int be = 0;
    {
        int tsel = lane >> 1, which = lane & 1;
        if (tsel < NT)
            be = rowptr[(size_t)tsel * (N + 1) + min(rbase + which * 32, N)];
    }

    for (int tt = 0; tt < NT; ++tt) {
        const int* cj = col + (size_t)tt * E;
        const int* rw = rowid + (size_t)tt * E;
        // zero wave's S region (flat 4096 floats)
        float4 z4 = {0.f, 0.f, 0.f, 0.f};
#pragma unroll
        for (int i = 0; i < 16; ++i)
            *(float4*)&G[rowb * 128 + i * 256 + lane * 4] = z4;

        int beg = __builtin_amdgcn_readlane(be, 2 * tt);
        int end = __builtin_amdgcn_readlane(be, 2 * tt + 1);
        int tot = end - beg;
        // prefetch up to 128 edges, packed v | (ulocal<<25)  (N < 2^25)
        unsigned p0 = 0, p1 = 0;
        if (lane < tot)
            p0 = (unsigned)cj[beg + lane] |
                 ((unsigned)(rw[beg + lane] - rbase) << 25);
        if (64 + lane < tot)
            p1 = (unsigned)cj[beg + 64 + lane] |
                 ((unsigned)(rw[beg + 64 + lane] - rbase) << 25);
        int klim = min(tot, 128);
        int kk = 0;
        // phase-batched main loop: 16 independent row loads, then 32 ds_adds
        for (; kk + 16 <= klim; kk += 16) {
            float2 y[16];
            unsigned pk[16];
#pragma unroll
            for (int b = 0; b < 16; ++b) {
                int k = kk + b;
                unsigned pa = __builtin_amdgcn_readlane(p0, k & 63);
                unsigned pb = __builtin_amdgcn_readlane(p1, k & 63);
                unsigned p = (k < 64) ? pa : pb;
                pk[b] = p;
                y[b] = *(const float2*)&Fin[(size_t)(p & 0x1FFFFFFu) * D + lc];
            }
#pragma unroll
            for (int b = 0; b < 16; ++b) {
                int a = gsw(rowb + (int)(pk[b] >> 25), lc);
                atomicAdd(&G[a], y[b].x);
                atomicAdd(&G[a + 1], y[b].y);
            }
        }
        for (; kk < klim; ++kk) {
            unsigned pa = __builtin_amdgcn_readlane(p0, kk & 63);
            unsigned pb = __builtin_amdgcn_readlane(p1, kk & 63);
            unsigned p = (kk < 64) ? pa : pb;
            float2 y = *(const float2*)&Fin[(size_t)(p & 0x1FFFFFFu) * D + lc];
            int a = gsw(rowb + (int)(p >> 25), lc);
            atomicAdd(&G[a], y.x);
            atomicAdd(&G[a + 1], y.y);
        }
        for (int k = 128; k < tot; ++k) {  // overflow (deg sum > 128): rare
            int v = cj[beg + k], u = rw[beg + k];
            float2 y = *(const float2*)&Fin[(size_t)v * D + lc];
            int a = gsw(rowb + (u - rbase), lc);
            atomicAdd(&G[a], y.x);
            atomicAdd(&G[a + 1], y.y);
        }
        pass_lds(acc, G, rowb, WL + (size_t)tt * MATSZ, fr, fq);
    }

    // GroupNorm(1,D) + affine + relu, fully in-register
    float gv[8], bv[8];
#pragma unroll
    for (int n = 0; n < 8; ++n) { gv[n] = ng[n * 16 + fr]; bv[n] = nb[n * 16 + fr]; }
#pragma unroll
    for (int m = 0; m < 2; ++m)
#pragma unroll
        for (int j = 0; j < 4; ++j) {
            float s = 0.f, q = 0.f;
#pragma unroll
            for (int n = 0; n < 8; ++n) { float x = acc[m][n][j]; s += x; q += x * x; }
#pragma unroll
            for (int o = 1; o <= 8; o <<= 1) { s += __shfl_xor(s, o); q += __shfl_xor(q, o); }
            float mu = s * (1.f / 128.f);
            float var = q * (1.f / 128.f) - mu * mu;
            float rs = rsqrtf(var + 1e-5f);
#pragma unroll
            for (int n = 0; n < 8; ++n)
                acc[m][n][j] = fmaxf(fmaf((acc[m][n][j] - mu) * rs, gv[n], bv[n]), 0.f);
        }

    // MLP1: H = relu(T@W1 + b1)
    store_lds_C(acc, G, rowb, fr, fq);
    zero_acc(acc);
    pass_lds(acc, G, rowb, Wcvt + (size_t)(2 + li) * MATSZ, fr, fq);
    float b1v[8], b2v[8];
#pragma unroll
    for (int n = 0; n < 8; ++n) { b1v[n] = mb1[n * 16 + fr]; b2v[n] = mb2[n * 16 + fr]; }
#pragma unroll
    for (int m = 0; m < 2; ++m)
#pragma unroll
        for (int n = 0; n < 8; ++n)
#pragma unroll
            for (int j = 0; j < 4; ++j)
                acc[m][n][j] = fmaxf(acc[m][n][j] + b1v[n], 0.f);

    // MLP2 + residual + relu
    store_lds_C(acc, G, rowb, fr, fq);
    zero_acc(acc);
    pass_lds(acc, G, rowb, Wcvt + (size_t)(6 + li) * MATSZ, fr, fq);
#pragma unroll
    for (int m = 0; m < 2; ++m)
#pragma unroll
        for (int j = 0; j < 4; ++j) {
            int row = rbase + m * 16 + fq * 4 + j;
            if (row < N) {
#pragma unroll
                for (int n = 0; n < 8; ++n) {
                    int c = n * 16 + fr;
                    float r = acc[m][n][j] + b2v[n] + Fin[(size_t)row * D + c];
                    Fout[(size_t)row * D + c] = fmaxf(r, 0.f);
                }
            }
        }
}

// ---------------------------------------------------------------------------
// Fused input: F = relu(h1@W2_in + b_in2 + h2@W2_seg + b_seg2)
// ---------------------------------------------------------------------------
__global__ __launch_bounds__(256) void input_fused_kernel(
    const float* __restrict__ ctrs, const float* __restrict__ feats,
    const float* __restrict__ inW1, const float* __restrict__ inb1,
    const float* __restrict__ segW1, const float* __restrict__ segb1,
    const float* __restrict__ inb2, const float* __restrict__ segb2,
    const unsigned short* __restrict__ Wcvt, float* __restrict__ Fout, int N) {
    __shared__ float G[128 * 128];
    int t = threadIdx.x, wave = t >> 6, lane = t & 63;
    int fr = lane & 15, fq = lane >> 4;
    int rbase = blockIdx.x * 128 + wave * 32;
    int rowb = wave * 32;
    int c0 = lane * 2;

    float iw0 = inW1[2 * c0], iw1 = inW1[2 * c0 + 1], iw2 = inW1[2 * c0 + 2],
          iw3 = inW1[2 * c0 + 3];
    float ib0 = inb1[c0], ib1 = inb1[c0 + 1];
    float sw0 = segW1[2 * c0], sw1 = segW1[2 * c0 + 1], sw2 = segW1[2 * c0 + 2],
          sw3 = segW1[2 * c0 + 3];
    float sb0 = segb1[c0], sb1 = segb1[c0 + 1];

    f32x4 acc[2][8];
    zero_acc(acc);

    for (int r = 0; r < 32; ++r) {
        int u = rbase + r;
        float2 h = {0.f, 0.f};
        if (u < N) {
            float2 x = *(const float2*)&ctrs[2 * (size_t)u];
            h.x = fmaxf(fmaf(x.x, iw0, fmaf(x.y, iw1, ib0)), 0.f);
            h.y = fmaxf(fmaf(x.x, iw2, fmaf(x.y, iw3, ib1)), 0.f);
        }
        *(float2*)(G + gsw(rowb + r, c0)) = h;
    }
    pass_lds(acc, G, rowb, Wcvt + (size_t)0 * MATSZ, fr, fq);

    for (int r = 0; r < 32; ++r) {
        int u = rbase + r;
        float2 h = {0.f, 0.f};
        if (u < N) {
            float2 x = *(const float2*)&feats[2 * (size_t)u];
            h.x = fmaxf(fmaf(x.x, sw0, fmaf(x.y, sw1, sb0)), 0.f);
            h.y = fmaxf(fmaf(x.x, sw2, fmaf(x.y, sw3, sb1)), 0.f);
        }
        *(float2*)(G + gsw(rowb + r, c0)) = h;
    }
    pass_lds(acc, G, rowb, Wcvt + (size_t)1 * MATSZ, fr, fq);

    float bi[8], bs[8];
#pragma unroll
    for (int n = 0; n < 8; ++n) { bi[n] = inb2[n * 16 + fr]; bs[n] = segb2[n * 16 + fr]; }
#pragma unroll
    for (int m = 0; m < 2; ++m)
#pragma unroll
        for (int j = 0; j < 4; ++j) {
            int row = rbase + m * 16 + fq * 4 + j;
            if (row < N) {
#pragma unroll
                for (int n = 0; n < 8; ++n)
                    Fout[(size_t)row * D + n * 16 + fr] =
                        fmaxf(acc[m][n][j] + bi[n] + bs[n], 0.f);
            }
        }
}

// ---------------------------------------------------------------------------
// Fused meta: out = relu([F, embed[mark]]@W1 + b1)@W2 + b2
// ---------------------------------------------------------------------------
__global__ __launch_bounds__(256) void meta_fused_kernel(
    const float* __restrict__ F, const int* __restrict__ mark,
    const float* __restrict__ embed, const float* __restrict__ mb1,
    const float* __restrict__ mb2, const unsigned short* __restrict__ Wcvt,
    float* __restrict__ out, int N) {
    __shared__ float G[128 * 128];
    int t = threadIdx.x, wave = t >> 6, lane = t & 63;
    int fr = lane & 15, fq = lane >> 4;
    int rbase = blockIdx.x * 128 + wave * 32;
    int rowb = wave * 32;
    int c0 = lane * 2;

    f32x4 acc[2][8];
    zero_acc(acc);
    pass_glb(acc, F, rbase, N, Wcvt + (size_t)54 * MATSZ, fr, fq);

    for (int r = 0; r < 32; ++r) {
        int u = rbase + r;
        float2 y = {0.f, 0.f};
        if (u < N) {
            int idx = mark[u];
            y = *(const float2*)&embed[(size_t)idx * D + c0];
        }
        *(float2*)(G + gsw(rowb + r, c0)) = y;
    }
    pass_lds(acc, G, rowb, Wcvt + (size_t)55 * MATSZ, fr, fq);

    float b1v[8], b2v[8];
#pragma unroll
    for (int n = 0; n < 8; ++n) { b1v[n] = mb1[n * 16 + fr]; b2v[n] = mb2[n * 16 + fr]; }
#pragma unroll
    for (int m = 0; m < 2; ++m)
#pragma unroll
        for (int n = 0; n < 8; ++n)
#pragma unroll
            for (int j = 0; j < 4; ++j)
                acc[m][n][j] = fmaxf(acc[m][n][j] + b1v[n], 0.f);

    store_lds_C(acc, G, rowb, fr, fq);
    zero_acc(acc);
    pass_lds(acc, G, rowb, Wcvt + (size_t)56 * MATSZ, fr, fq);
#pragma unroll
    for (int m = 0; m < 2; ++m)
#pragma unroll
        for (int j = 0; j < 4; ++j) {
            int row = rbase + m * 16 + fq * 4 + j;
            if (row < N) {
#pragma unroll
                for (int n = 0; n < 8; ++n)
                    out[(size_t)row * D + n * 16 + fr] = acc[m][n][j] + b2v[n];
            }
        }
}

// ---------------------------------------------------------------------------
// weight pre-conversion (unchanged, proven)
// ---------------------------------------------------------------------------
__global__ __launch_bounds__(256) void wcvt_kernel(CvtTab tab,
                                                   unsigned short* dst) {
    int bid = blockIdx.x;
    int mat = bid >> 4;
    if (mat >= NMAT) return;
    int e = (bid & 15) * 1024 + threadIdx.x * 4;
    int o = e >> 7, k = e & 127;
    const float* s = tab.src[mat];
    int ldw = tab.ldw[mat];
    float4 v = *(const float4*)&s[(size_t)o * ldw + k];
    ushort4 h, l;
    h.x = f2bf(v.x); l.x = f2bf(v.x - bf2f(h.x));
    h.y = f2bf(v.y); l.y = f2bf(v.y - bf2f(h.y));
    h.z = f2bf(v.z); l.z = f2bf(v.z - bf2f(h.z));
    h.w = f2bf(v.w); l.w = f2bf(v.w - bf2f(h.w));
    *(ushort4*)&dst[(size_t)mat * MATSZ + e] = h;
    *(ushort4*)&dst[(size_t)mat * MATSZ + 16384 + e] = l;
}

// ---------------------------------------------------------------------------
// CSR build (unchanged)
// ---------------------------------------------------------------------------
__global__ void csr_hist_kernel(const int* __restrict__ edge_u, int* deg,
                                int N, int E) {
    int gid = blockIdx.x * blockDim.x + threadIdx.x;
    if (gid >= NT * E) return;
    int t = gid / E;
    int u = edge_u[gid];
    atomicAdd(&deg[(size_t)t * N + u], 1);
}

__global__ __launch_bounds__(256) void csr_chunksum_kernel(
    const int* __restrict__ deg, int* csum, int N, int nch) {
    int b = blockIdx.x;
    int t = b / nch, ch = b % nch;
    int tid = threadIdx.x;
    const int* dg = deg + (size_t)t * N;
    int base = ch * SCH + tid * 4;
    int s = 0;
#pragma unroll
    for (int j = 0; j < 4; ++j) {
        int idx = base + j;
        if (idx < N) s += dg[idx];
    }
#pragma unroll
    for (int off = 32; off; off >>= 1) s += __shfl_down(s, off);
    __shared__ int wsum[4];
    if ((tid & 63) == 0) wsum[tid >> 6] = s;
    __syncthreads();
    if (tid == 0) csum[b] = wsum[0] + wsum[1] + wsum[2] + wsum[3];
}

__global__ void csr_chunkscan_kernel(int* csum, int* rowptr, int N, int nch) {
    int t = threadIdx.x;
    if (t >= NT) return;
    int run = 0;
    for (int i = 0; i < nch; ++i) {
        int v = csum[t * nch + i];
        csum[t * nch + i] = run;
        run += v;
    }
    rowptr[(size_t)t * (N + 1) + N] = run;
}

__global__ __launch_bounds__(256) void csr_blockscan_kernel(
    const int* __restrict__ deg, const int* __restrict__ csum, int* rowptr,
    int* cur, int N, int nch) {
    int b = blockIdx.x;
    int t = b / nch, ch = b % nch;
    int tid = threadIdx.x;
    const int* dg = deg + (size_t)t * N;
    int base = ch * SCH + tid * 4;
    int d[4];
    int s = 0;
#pragma unroll
    for (int j = 0; j < 4; ++j) {
        int idx = base + j;
        d[j] = (idx < N) ? dg[idx] : 0;
        s += d[j];
    }
    __shared__ int ps[256];
    ps[tid] = s;
    __syncthreads();
    for (int off = 1; off < 256; off <<= 1) {
        int v = (tid >= off) ? ps[tid - off] : 0;
        __syncthreads();
        ps[tid] += v;
        __syncthreads();
    }
    int excl = (tid ? ps[tid - 1] : 0) + csum[b];
    size_t rb = (size_t)t * (N + 1);
#pragma unroll
    for (int j = 0; j < 4; ++j) {
        int idx = base + j;
        if (idx < N) {
            rowptr[rb + idx] = excl;
            cur[rb + idx] = excl;
            excl += d[j];
        }
    }
}

__global__ void csr_fill_kernel(const int* __restrict__ edge_u,
                                const int* __restrict__ edge_v, int* cur,
                                int* col, int* rowid, int N, int E) {
    int gid = blockIdx.x * blockDim.x + threadIdx.x;
    if (gid >= NT * E) return;
    int t = gid / E;
    int u = edge_u[gid];
    int v = edge_v[gid];
    int pos = atomicAdd(&cur[(size_t)t * (N + 1) + u], 1);
    col[(size_t)t * E + pos] = v;
    rowid[(size_t)t * E + pos] = u;
}

// ---------------------------------------------------------------------------
extern "C" void kernel_launch(void* const* d_in, const int* in_sizes, int n_in,
                              void* d_out, int out_size, void* d_ws,
                              size_t ws_size, hipStream_t stream) {
    const float* ctrs = (const float*)d_in[0];
    const float* feats = (const float*)d_in[1];
    const float* in_W1 = (const float*)d_in[2];
    const float* in_b1 = (const float*)d_in[3];
    const float* in_W2 = (const float*)d_in[4];
    const float* in_b2 = (const float*)d_in[5];
    const float* seg_W1 = (const float*)d_in[6];
    const float* seg_b1 = (const float*)d_in[7];
    const float* seg_W2 = (const float*)d_in[8];
    const float* seg_b2 = (const float*)d_in[9];
    const float* embed = (const float*)d_in[10];
    const float* meta_W1 = (const float*)d_in[11];
    const float* meta_b1 = (const float*)d_in[12];
    const float* meta_W2 = (const float*)d_in[13];
    const float* meta_b2 = (const float*)d_in[14];
    const float* ctr_W = (const float*)d_in[15];
    const float* edge_W = (const float*)d_in[16];
    const float* norm_g = (const float*)d_in[17];
    const float* norm_b = (const float*)d_in[18];
    const float* ctr2_W1 = (const float*)d_in[19];
    const float* ctr2_b1 = (const float*)d_in[20];
    const float* ctr2_W2 = (const float*)d_in[21];
    const float* ctr2_b2 = (const float*)d_in[22];
    const int* mark_type = (const int*)d_in[23];
    const int* edge_u = (const int*)d_in[24];
    const int* edge_v = (const int*)d_in[25];

    const int N = in_sizes[0] / 2;
    const int E = in_sizes[24] / NT;
    const size_t ND = (size_t)N * D;
    const int nch = (N + SCH - 1) / SCH;

    // ws layout: [Wcvt 3.7MB | FA 77MB | FB 77MB | rowptr 6MB | col 6MB]
    unsigned short* Wcvt = (unsigned short*)d_ws;
    size_t wcB = ((size_t)NMAT * MATSZ * sizeof(unsigned short) + 255) & ~(size_t)255;
    float* FA = (float*)((char*)d_ws + wcB);
    float* FB = FA + ND;
    int* rowptr = (int*)(FB + ND);
    int* col = rowptr + (size_t)NT * (N + 1);

    // d_out scratch: rowid (persists through layers) + CSR-build temps
    int* rowid = (int*)d_out;                      // NT*E
    int* deg = rowid + (size_t)NT * E;             // NT*N
    int* cur = deg + (size_t)NT * N;               // NT*(N+1)
    int* csum = cur + (size_t)NT * (N + 1);        // NT*nch

    // weight conversion table
    CvtTab tab;
    tab.src[0] = in_W2;  tab.ldw[0] = D;
    tab.src[1] = seg_W2; tab.ldw[1] = D;
    for (int i = 0; i < NL; ++i) { tab.src[2 + i] = ctr2_W1 + (size_t)i * D * D; tab.ldw[2 + i] = D; }
    for (int i = 0; i < NL; ++i) { tab.src[6 + i] = ctr2_W2 + (size_t)i * D * D; tab.ldw[6 + i] = D; }
    for (int i = 0; i < NL; ++i) {
        for (int t = 0; t < NT; ++t) {
            int id = 10 + i * 11 + t;
            tab.src[id] = edge_W + ((size_t)i * NT + t) * D * D;
            tab.ldw[id] = D;
        }
        tab.src[10 + i * 11 + 10] = ctr_W + (size_t)i * D * D;
        tab.ldw[10 + i * 11 + 10] = D;
    }
    tab.src[54] = meta_W1;     tab.ldw[54] = 2 * D;
    tab.src[55] = meta_W1 + D; tab.ldw[55] = 2 * D;
    tab.src[56] = meta_W2;     tab.ldw[56] = D;
    wcvt_kernel<<<NMAT * 16, 256, 0, stream>>>(tab, Wcvt);

    dim3 blk(256);
    dim3 gTE(((size_t)NT * E + 255) / 256);
    int nblk = (N + 127) / 128;

    // CSR build
    hipMemsetAsync(deg, 0, (size_t)NT * N * sizeof(int), stream);
    csr_hist_kernel<<<gTE, blk, 0, stream>>>(edge_u, deg, N, E);
    csr_chunksum_kernel<<<NT * nch, blk, 0, stream>>>(deg, csum, N, nch);
    csr_chunkscan_kernel<<<1, 64, 0, stream>>>(csum, rowptr, N, nch);
    csr_blockscan_kernel<<<NT * nch, blk, 0, stream>>>(deg, csum, rowptr, cur, N, nch);
    csr_fill_kernel<<<gTE, blk, 0, stream>>>(edge_u, edge_v, cur, col, rowid, N, E);

    // input stage -> FA
    input_fused_kernel<<<nblk, blk, 0, stream>>>(ctrs, feats, in_W1, in_b1,
                                                 seg_W1, seg_b1, in_b2, seg_b2,
                                                 Wcvt, FA, N);

    // 4 fused layers, ping-pong FA <-> FB
    float* Fi = FA;
    float* Fo = FB;
    for (int i = 0; i < NL; ++i) {
        layer_fused_kernel<<<nblk, blk, 0, stream>>>(
            Fi, Fo, Wcvt, i, rowptr, col, rowid, norm_g + (size_t)i * D,
            norm_b + (size_t)i * D, ctr2_b1 + (size_t)i * D,
            ctr2_b2 + (size_t)i * D, N, E);
        float* tmp = Fi; Fi = Fo; Fo = tmp;
    }

    // meta stage -> d_out  (rowid no longer needed)
    meta_fused_kernel<<<nblk, blk, 0, stream>>>(Fi, mark_type, embed, meta_b1,
                                                meta_b2, Wcvt, (float*)d_out, N);
}

// Round 9
// 5748.663 us; speedup vs baseline: 1.1919x; 1.0988x over previous
//
#include <hip/hip_runtime.h>

#define D 128
#define NT 10    // edge types
#define NL 4     // layers
#define SCH 1024 // nodes per scan chunk
#define NMAT 57
#define MATSZ 32768  // shorts per converted matrix (hi 16384 + lo 16384)
#define WR 16        // rows per wave
#define BR 64        // rows per block (4 waves)

typedef __attribute__((ext_vector_type(8))) short bf16x8;
typedef __attribute__((ext_vector_type(4))) float f32x4;

struct CvtTab { const float* src[NMAT]; int ldw[NMAT]; };

__device__ inline unsigned short f2bf(float x) {
    union { float f; unsigned u; } v; v.f = x;
    unsigned r = v.u + 0x7FFFu + ((v.u >> 16) & 1u);
    return (unsigned short)(r >> 16);
}
__device__ inline float bf2f(unsigned short h) {
    union { unsigned u; float f; } v; v.u = ((unsigned)h) << 16;
    return v.f;
}
__device__ inline void cvt8(const float4& v0, const float4& v1, bf16x8& h,
                            bf16x8& l) {
    float f[8] = {v0.x, v0.y, v0.z, v0.w, v1.x, v1.y, v1.z, v1.w};
#pragma unroll
    for (int j = 0; j < 8; ++j) {
        unsigned short hh = f2bf(f[j]);
        h[j] = (short)hh;
        l[j] = (short)f2bf(f[j] - bf2f(hh));
    }
}
__device__ inline f32x4 MF(bf16x8 a, bf16x8 b, f32x4 c) {
    return __builtin_amdgcn_mfma_f32_16x16x32_bf16(a, b, c, 0, 0, 0);
}

// XOR-granule swizzle within each 128-float row (bank spread for ds ops)
__device__ inline int gsw(int row, int c) {
    return (row << 7) + (((((c >> 2) ^ ((row & 7) << 2)) & 31) << 2) | (c & 3));
}

// MFMA pass, A = 16 fp32 rows [rowb..rowb+16) of the swizzled LDS tile
__device__ inline void pass_lds(f32x4 (&acc)[8], const float* G, int rowb,
                                const unsigned short* Wm, int fr, int fq) {
#pragma unroll
    for (int kc = 0; kc < 4; ++kc) {
        int ko = kc * 32 + fq * 8;
        int row = rowb + fr;
        float4 v0 = *(const float4*)(G + gsw(row, ko));
        float4 v1 = *(const float4*)(G + gsw(row, ko + 4));
        bf16x8 ah, al;
        cvt8(v0, v1, ah, al);
#pragma unroll
        for (int n = 0; n < 8; ++n) {
            const unsigned short* wp = Wm + (size_t)(n * 16 + fr) * D + ko;
            bf16x8 wh = *(const bf16x8*)wp;
            bf16x8 wl = *(const bf16x8*)(wp + 16384);
            acc[n] = MF(ah, wh, acc[n]);
            acc[n] = MF(ah, wl, acc[n]);
            acc[n] = MF(al, wh, acc[n]);
        }
    }
}

// MFMA pass, A = 16 fp32 rows straight from global (row-guarded)
__device__ inline void pass_glb(f32x4 (&acc)[8], const float* A, int rbase,
                                int N, const unsigned short* Wm, int fr,
                                int fq) {
    int r0 = rbase + fr;
    const float* a0 = A + (size_t)r0 * D;
    bool ok0 = r0 < N;
#pragma unroll
    for (int kc = 0; kc < 4; ++kc) {
        int ko = kc * 32 + fq * 8;
        float4 v0 = {0, 0, 0, 0}, v1 = {0, 0, 0, 0};
        if (ok0) { v0 = *(const float4*)(a0 + ko); v1 = *(const float4*)(a0 + ko + 4); }
        bf16x8 ah, al;
        cvt8(v0, v1, ah, al);
#pragma unroll
        for (int n = 0; n < 8; ++n) {
            const unsigned short* wp = Wm + (size_t)(n * 16 + fr) * D + ko;
            bf16x8 wh = *(const bf16x8*)wp;
            bf16x8 wl = *(const bf16x8*)(wp + 16384);
            acc[n] = MF(ah, wh, acc[n]);
            acc[n] = MF(ah, wl, acc[n]);
            acc[n] = MF(al, wh, acc[n]);
        }
    }
}

__device__ inline void zero_acc(f32x4 (&acc)[8]) {
#pragma unroll
    for (int n = 0; n < 8; ++n) acc[n] = (f32x4){0.f, 0.f, 0.f, 0.f};
}

// write acc (C layout: row=fq*4+j, col=n*16+fr) into the LDS tile
__device__ inline void store_lds_C(const f32x4 (&acc)[8], float* G, int rowb,
                                   int fr, int fq) {
#pragma unroll
    for (int j = 0; j < 4; ++j) {
        int row = rowb + fq * 4 + j;
#pragma unroll
        for (int n = 0; n < 8; ++n) G[gsw(row, n * 16 + fr)] = acc[n][j];
    }
}

// ---------------------------------------------------------------------------
// Fused layer, occupancy-first: 16-row waves, 64-row blocks, 32 KB LDS,
// capped at 128 VGPR. No barriers — waves co-schedule gather vs MFMA.
// ---------------------------------------------------------------------------
__global__ __launch_bounds__(256, 4) void layer_fused_kernel(
    const float* __restrict__ Fin, float* __restrict__ Fout,
    const unsigned short* __restrict__ Wcvt, int li,
    const int* __restrict__ rowptr, const int* __restrict__ col,
    const int* __restrict__ rowid, const float* __restrict__ ng,
    const float* __restrict__ nb, const float* __restrict__ mb1,
    const float* __restrict__ mb2, int N, int E) {
    __shared__ float G[BR * 128];
    int t = threadIdx.x, wave = t >> 6, lane = t & 63;
    int fr = lane & 15, fq = lane >> 4;
    int rbase = blockIdx.x * BR + wave * WR;
    int rowb = wave * WR;
    int lc = lane << 1;

    f32x4 acc[8];
    zero_acc(acc);

    const unsigned short* WL = Wcvt + (size_t)(10 + li * 11) * MATSZ;
    // ctr term: A = Fin rows streamed from global
    pass_glb(acc, Fin, rbase, N, WL + (size_t)10 * MATSZ, fr, fq);

    // hoisted beg/end for all 10 types: lane 2t -> rp_t[rbase], 2t+1 -> rp_t[rbase+16]
    int be = 0;
    {
        int tsel = lane >> 1, which = lane & 1;
        if (tsel < NT)
            be = rowptr[(size_t)tsel * (N + 1) + min(rbase + which * WR, N)];
    }

    for (int tt = 0; tt < NT; ++tt) {
        int beg = __builtin_amdgcn_readlane(be, 2 * tt);
        int end = __builtin_amdgcn_readlane(be, 2 * tt + 1);
        int tot = end - beg;
        if (tot == 0) continue;  // S==0 -> contributes nothing
        const int* cj = col + (size_t)tt * E;
        const int* rw = rowid + (size_t)tt * E;
        // zero wave's S region (16 rows = 2048 floats)
        float4 z4 = {0.f, 0.f, 0.f, 0.f};
#pragma unroll
        for (int i = 0; i < 8; ++i)
            *(float4*)&G[rowb * 128 + i * 256 + lane * 4] = z4;

        // prefetch up to 64 edges, packed v | (ulocal<<25)  (N < 2^25)
        unsigned p0 = 0;
        if (lane < tot)
            p0 = (unsigned)cj[beg + lane] |
                 ((unsigned)(rw[beg + lane] - rbase) << 25);
        int klim = min(tot, 64);
        int kk = 0;
        for (; kk + 8 <= klim; kk += 8) {
            float2 y[8];
            unsigned pk[8];
#pragma unroll
            for (int b = 0; b < 8; ++b) {
                unsigned p = __builtin_amdgcn_readlane(p0, kk + b);
                pk[b] = p;
                y[b] = *(const float2*)&Fin[(size_t)(p & 0x1FFFFFFu) * D + lc];
            }
#pragma unroll
            for (int b = 0; b < 8; ++b) {
                int a = gsw(rowb + (int)(pk[b] >> 25), lc);
                atomicAdd(&G[a], y[b].x);
                atomicAdd(&G[a + 1], y[b].y);
            }
        }
        for (; kk < klim; ++kk) {
            unsigned p = __builtin_amdgcn_readlane(p0, kk);
            float2 y = *(const float2*)&Fin[(size_t)(p & 0x1FFFFFFu) * D + lc];
            int a = gsw(rowb + (int)(p >> 25), lc);
            atomicAdd(&G[a], y.x);
            atomicAdd(&G[a + 1], y.y);
        }
        for (int k = 64; k < tot; ++k) {  // overflow (rare)
            int v = cj[beg + k], u = rw[beg + k];
            float2 y = *(const float2*)&Fin[(size_t)v * D + lc];
            int a = gsw(rowb + (u - rbase), lc);
            atomicAdd(&G[a], y.x);
            atomicAdd(&G[a + 1], y.y);
        }
        pass_lds(acc, G, rowb, WL + (size_t)tt * MATSZ, fr, fq);
    }

    // GroupNorm(1,D) + affine + relu, fully in-register
    float gv[8], bv[8];
#pragma unroll
    for (int n = 0; n < 8; ++n) { gv[n] = ng[n * 16 + fr]; bv[n] = nb[n * 16 + fr]; }
#pragma unroll
    for (int j = 0; j < 4; ++j) {
        float s = 0.f, q = 0.f;
#pragma unroll
        for (int n = 0; n < 8; ++n) { float x = acc[n][j]; s += x; q += x * x; }
#pragma unroll
        for (int o = 1; o <= 8; o <<= 1) { s += __shfl_xor(s, o); q += __shfl_xor(q, o); }
        float mu = s * (1.f / 128.f);
        float var = q * (1.f / 128.f) - mu * mu;
        float rs = rsqrtf(var + 1e-5f);
#pragma unroll
        for (int n = 0; n < 8; ++n)
            acc[n][j] = fmaxf(fmaf((acc[n][j] - mu) * rs, gv[n], bv[n]), 0.f);
    }

    // MLP1: H = relu(T@W1 + b1)   (T bounced through wave-local LDS)
    store_lds_C(acc, G, rowb, fr, fq);
    zero_acc(acc);
    pass_lds(acc, G, rowb, Wcvt + (size_t)(2 + li) * MATSZ, fr, fq);
    float b1v[8], b2v[8];
#pragma unroll
    for (int n = 0; n < 8; ++n) { b1v[n] = mb1[n * 16 + fr]; b2v[n] = mb2[n * 16 + fr]; }
#pragma unroll
    for (int n = 0; n < 8; ++n)
#pragma unroll
        for (int j = 0; j < 4; ++j)
            acc[n][j] = fmaxf(acc[n][j] + b1v[n], 0.f);

    // MLP2 + residual + relu
    store_lds_C(acc, G, rowb, fr, fq);
    zero_acc(acc);
    pass_lds(acc, G, rowb, Wcvt + (size_t)(6 + li) * MATSZ, fr, fq);
#pragma unroll
    for (int j = 0; j < 4; ++j) {
        int row = rbase + fq * 4 + j;
        if (row < N) {
#pragma unroll
            for (int n = 0; n < 8; ++n) {
                int c = n * 16 + fr;
                float r = acc[n][j] + b2v[n] + Fin[(size_t)row * D + c];
                Fout[(size_t)row * D + c] = fmaxf(r, 0.f);
            }
        }
    }
}

// ---------------------------------------------------------------------------
// Fused input: F = relu(h1@W2_in + b_in2 + h2@W2_seg + b_seg2)
// ---------------------------------------------------------------------------
__global__ __launch_bounds__(256, 4) void input_fused_kernel(
    const float* __restrict__ ctrs, const float* __restrict__ feats,
    const float* __restrict__ inW1, const float* __restrict__ inb1,
    const float* __restrict__ segW1, const float* __restrict__ segb1,
    const float* __restrict__ inb2, const float* __restrict__ segb2,
    const unsigned short* __restrict__ Wcvt, float* __restrict__ Fout, int N) {
    __shared__ float G[BR * 128];
    int t = threadIdx.x, wave = t >> 6, lane = t & 63;
    int fr = lane & 15, fq = lane >> 4;
    int rbase = blockIdx.x * BR + wave * WR;
    int rowb = wave * WR;
    int c0 = lane * 2;

    float iw0 = inW1[2 * c0], iw1 = inW1[2 * c0 + 1], iw2 = inW1[2 * c0 + 2],
          iw3 = inW1[2 * c0 + 3];
    float ib0 = inb1[c0], ib1 = inb1[c0 + 1];
    float sw0 = segW1[2 * c0], sw1 = segW1[2 * c0 + 1], sw2 = segW1[2 * c0 + 2],
          sw3 = segW1[2 * c0 + 3];
    float sb0 = segb1[c0], sb1 = segb1[c0 + 1];

    f32x4 acc[8];
    zero_acc(acc);

    for (int r = 0; r < WR; ++r) {
        int u = rbase + r;
        float2 h = {0.f, 0.f};
        if (u < N) {
            float2 x = *(const float2*)&ctrs[2 * (size_t)u];
            h.x = fmaxf(fmaf(x.x, iw0, fmaf(x.y, iw1, ib0)), 0.f);
            h.y = fmaxf(fmaf(x.x, iw2, fmaf(x.y, iw3, ib1)), 0.f);
        }
        *(float2*)(G + gsw(rowb + r, c0)) = h;
    }
    pass_lds(acc, G, rowb, Wcvt + (size_t)0 * MATSZ, fr, fq);

    for (int r = 0; r < WR; ++r) {
        int u = rbase + r;
        float2 h = {0.f, 0.f};
        if (u < N) {
            float2 x = *(const float2*)&feats[2 * (size_t)u];
            h.x = fmaxf(fmaf(x.x, sw0, fmaf(x.y, sw1, sb0)), 0.f);
            h.y = fmaxf(fmaf(x.x, sw2, fmaf(x.y, sw3, sb1)), 0.f);
        }
        *(float2*)(G + gsw(rowb + r, c0)) = h;
    }
    pass_lds(acc, G, rowb, Wcvt + (size_t)1 * MATSZ, fr, fq);

    float bi[8], bs[8];
#pragma unroll
    for (int n = 0; n < 8; ++n) { bi[n] = inb2[n * 16 + fr]; bs[n] = segb2[n * 16 + fr]; }
#pragma unroll
    for (int j = 0; j < 4; ++j) {
        int row = rbase + fq * 4 + j;
        if (row < N) {
#pragma unroll
            for (int n = 0; n < 8; ++n)
                Fout[(size_t)row * D + n * 16 + fr] =
                    fmaxf(acc[n][j] + bi[n] + bs[n], 0.f);
        }
    }
}

// ---------------------------------------------------------------------------
// Fused meta: out = relu([F, embed[mark]]@W1 + b1)@W2 + b2
// ---------------------------------------------------------------------------
__global__ __launch_bounds__(256, 4) void meta_fused_kernel(
    const float* __restrict__ F, const int* __restrict__ mark,
    const float* __restrict__ embed, const float* __restrict__ mb1,
    const float* __restrict__ mb2, const unsigned short* __restrict__ Wcvt,
    float* __restrict__ out, int N) {
    __shared__ float G[BR * 128];
    int t = threadIdx.x, wave = t >> 6, lane = t & 63;
    int fr = lane & 15, fq = lane >> 4;
    int rbase = blockIdx.x * BR + wave * WR;
    int rowb = wave * WR;
    int c0 = lane * 2;

    f32x4 acc[8];
    zero_acc(acc);
    pass_glb(acc, F, rbase, N, Wcvt + (size_t)54 * MATSZ, fr, fq);

    for (int r = 0; r < WR; ++r) {
        int u = rbase + r;
        float2 y = {0.f, 0.f};
        if (u < N) {
            int idx = mark[u];
            y = *(const float2*)&embed[(size_t)idx * D + c0];
        }
        *(float2*)(G + gsw(rowb + r, c0)) = y;
    }
    pass_lds(acc, G, rowb, Wcvt + (size_t)55 * MATSZ, fr, fq);

    float b1v[8], b2v[8];
#pragma unroll
    for (int n = 0; n < 8; ++n) { b1v[n] = mb1[n * 16 + fr]; b2v[n] = mb2[n * 16 + fr]; }
#pragma unroll
    for (int n = 0; n < 8; ++n)
#pragma unroll
        for (int j = 0; j < 4; ++j)
            acc[n][j] = fmaxf(acc[n][j] + b1v[n], 0.f);

    store_lds_C(acc, G, rowb, fr, fq);
    zero_acc(acc);
    pass_lds(acc, G, rowb, Wcvt + (size_t)56 * MATSZ, fr, fq);
#pragma unroll
    for (int j = 0; j < 4; ++j) {
        int row = rbase + fq * 4 + j;
        if (row < N) {
#pragma unroll
            for (int n = 0; n < 8; ++n)
                out[(size_t)row * D + n * 16 + fr] = acc[n][j] + b2v[n];
        }
    }
}

// ---------------------------------------------------------------------------
// weight pre-conversion (unchanged, proven)
// ---------------------------------------------------------------------------
__global__ __launch_bounds__(256) void wcvt_kernel(CvtTab tab,
                                                   unsigned short* dst) {
    int bid = blockIdx.x;
    int mat = bid >> 4;
    if (mat >= NMAT) return;
    int e = (bid & 15) * 1024 + threadIdx.x * 4;
    int o = e >> 7, k = e & 127;
    const float* s = tab.src[mat];
    int ldw = tab.ldw[mat];
    float4 v = *(const float4*)&s[(size_t)o * ldw + k];
    ushort4 h, l;
    h.x = f2bf(v.x); l.x = f2bf(v.x - bf2f(h.x));
    h.y = f2bf(v.y); l.y = f2bf(v.y - bf2f(h.y));
    h.z = f2bf(v.z); l.z = f2bf(v.z - bf2f(h.z));
    h.w = f2bf(v.w); l.w = f2bf(v.w - bf2f(h.w));
    *(ushort4*)&dst[(size_t)mat * MATSZ + e] = h;
    *(ushort4*)&dst[(size_t)mat * MATSZ + 16384 + e] = l;
}

// ---------------------------------------------------------------------------
// CSR build (unchanged)
// ---------------------------------------------------------------------------
__global__ void csr_hist_kernel(const int* __restrict__ edge_u, int* deg,
                                int N, int E) {
    int gid = blockIdx.x * blockDim.x + threadIdx.x;
    if (gid >= NT * E) return;
    int t = gid / E;
    int u = edge_u[gid];
    atomicAdd(&deg[(size_t)t * N + u], 1);
}

__global__ __launch_bounds__(256) void csr_chunksum_kernel(
    const int* __restrict__ deg, int* csum, int N, int nch) {
    int b = blockIdx.x;
    int t = b / nch, ch = b % nch;
    int tid = threadIdx.x;
    const int* dg = deg + (size_t)t * N;
    int base = ch * SCH + tid * 4;
    int s = 0;
#pragma unroll
    for (int j = 0; j < 4; ++j) {
        int idx = base + j;
        if (idx < N) s += dg[idx];
    }
#pragma unroll
    for (int off = 32; off; off >>= 1) s += __shfl_down(s, off);
    __shared__ int wsum[4];
    if ((tid & 63) == 0) wsum[tid >> 6] = s;
    __syncthreads();
    if (tid == 0) csum[b] = wsum[0] + wsum[1] + wsum[2] + wsum[3];
}

__global__ void csr_chunkscan_kernel(int* csum, int* rowptr, int N, int nch) {
    int t = threadIdx.x;
    if (t >= NT) return;
    int run = 0;
    for (int i = 0; i < nch; ++i) {
        int v = csum[t * nch + i];
        csum[t * nch + i] = run;
        run += v;
    }
    rowptr[(size_t)t * (N + 1) + N] = run;
}

__global__ __launch_bounds__(256) void csr_blockscan_kernel(
    const int* __restrict__ deg, const int* __restrict__ csum, int* rowptr,
    int* cur, int N, int nch) {
    int b = blockIdx.x;
    int t = b / nch, ch = b % nch;
    int tid = threadIdx.x;
    const int* dg = deg + (size_t)t * N;
    int base = ch * SCH + tid * 4;
    int d[4];
    int s = 0;
#pragma unroll
    for (int j = 0; j < 4; ++j) {
        int idx = base + j;
        d[j] = (idx < N) ? dg[idx] : 0;
        s += d[j];
    }
    __shared__ int ps[256];
    ps[tid] = s;
    __syncthreads();
    for (int off = 1; off < 256; off <<= 1) {
        int v = (tid >= off) ? ps[tid - off] : 0;
        __syncthreads();
        ps[tid] += v;
        __syncthreads();
    }
    int excl = (tid ? ps[tid - 1] : 0) + csum[b];
    size_t rb = (size_t)t * (N + 1);
#pragma unroll
    for (int j = 0; j < 4; ++j) {
        int idx = base + j;
        if (idx < N) {
            rowptr[rb + idx] = excl;
            cur[rb + idx] = excl;
            excl += d[j];
        }
    }
}

__global__ void csr_fill_kernel(const int* __restrict__ edge_u,
                                const int* __restrict__ edge_v, int* cur,
                                int* col, int* rowid, int N, int E) {
    int gid = blockIdx.x * blockDim.x + threadIdx.x;
    if (gid >= NT * E) return;
    int t = gid / E;
    int u = edge_u[gid];
    int v = edge_v[gid];
    int pos = atomicAdd(&cur[(size_t)t * (N + 1) + u], 1);
    col[(size_t)t * E + pos] = v;
    rowid[(size_t)t * E + pos] = u;
}

// ---------------------------------------------------------------------------
extern "C" void kernel_launch(void* const* d_in, const int* in_sizes, int n_in,
                              void* d_out, int out_size, void* d_ws,
                              size_t ws_size, hipStream_t stream) {
    const float* ctrs = (const float*)d_in[0];
    const float* feats = (const float*)d_in[1];
    const float* in_W1 = (const float*)d_in[2];
    const float* in_b1 = (const float*)d_in[3];
    const float* in_W2 = (const float*)d_in[4];
    const float* in_b2 = (const float*)d_in[5];
    const float* seg_W1 = (const float*)d_in[6];
    const float* seg_b1 = (const float*)d_in[7];
    const float* seg_W2 = (const float*)d_in[8];
    const float* seg_b2 = (const float*)d_in[9];
    const float* embed = (const float*)d_in[10];
    const float* meta_W1 = (const float*)d_in[11];
    const float* meta_b1 = (const float*)d_in[12];
    const float* meta_W2 = (const float*)d_in[13];
    const float* meta_b2 = (const float*)d_in[14];
    const float* ctr_W = (const float*)d_in[15];
    const float* edge_W = (const float*)d_in[16];
    const float* norm_g = (const float*)d_in[17];
    const float* norm_b = (const float*)d_in[18];
    const float* ctr2_W1 = (const float*)d_in[19];
    const float* ctr2_b1 = (const float*)d_in[20];
    const float* ctr2_W2 = (const float*)d_in[21];
    const float* ctr2_b2 = (const float*)d_in[22];
    const int* mark_type = (const int*)d_in[23];
    const int* edge_u = (const int*)d_in[24];
    const int* edge_v = (const int*)d_in[25];

    const int N = in_sizes[0] / 2;
    const int E = in_sizes[24] / NT;
    const size_t ND = (size_t)N * D;
    const int nch = (N + SCH - 1) / SCH;

    // ws layout: [Wcvt 3.7MB | FA 77MB | FB 77MB | rowptr 6MB | col 6MB]
    unsigned short* Wcvt = (unsigned short*)d_ws;
    size_t wcB = ((size_t)NMAT * MATSZ * sizeof(unsigned short) + 255) & ~(size_t)255;
    float* FA = (float*)((char*)d_ws + wcB);
    float* FB = FA + ND;
    int* rowptr = (int*)(FB + ND);
    int* col = rowptr + (size_t)NT * (N + 1);

    // d_out scratch: rowid (persists through layers) + CSR-build temps
    int* rowid = (int*)d_out;                      // NT*E
    int* deg = rowid + (size_t)NT * E;             // NT*N
    int* cur = deg + (size_t)NT * N;               // NT*(N+1)
    int* csum = cur + (size_t)NT * (N + 1);        // NT*nch

    // weight conversion table
    CvtTab tab;
    tab.src[0] = in_W2;  tab.ldw[0] = D;
    tab.src[1] = seg_W2; tab.ldw[1] = D;
    for (int i = 0; i < NL; ++i) { tab.src[2 + i] = ctr2_W1 + (size_t)i * D * D; tab.ldw[2 + i] = D; }
    for (int i = 0; i < NL; ++i) { tab.src[6 + i] = ctr2_W2 + (size_t)i * D * D; tab.ldw[6 + i] = D; }
    for (int i = 0; i < NL; ++i) {
        for (int t = 0; t < NT; ++t) {
            int id = 10 + i * 11 + t;
            tab.src[id] = edge_W + ((size_t)i * NT + t) * D * D;
            tab.ldw[id] = D;
        }
        tab.src[10 + i * 11 + 10] = ctr_W + (size_t)i * D * D;
        tab.ldw[10 + i * 11 + 10] = D;
    }
    tab.src[54] = meta_W1;     tab.ldw[54] = 2 * D;
    tab.src[55] = meta_W1 + D; tab.ldw[55] = 2 * D;
    tab.src[56] = meta_W2;     tab.ldw[56] = D;
    wcvt_kernel<<<NMAT * 16, 256, 0, stream>>>(tab, Wcvt);

    dim3 blk(256);
    dim3 gTE(((size_t)NT * E + 255) / 256);
    int nblk = (N + BR - 1) / BR;

    // CSR build
    hipMemsetAsync(deg, 0, (size_t)NT * N * sizeof(int), stream);
    csr_hist_kernel<<<gTE, blk, 0, stream>>>(edge_u, deg, N, E);
    csr_chunksum_kernel<<<NT * nch, blk, 0, stream>>>(deg, csum, N, nch);
    csr_chunkscan_kernel<<<1, 64, 0, stream>>>(csum, rowptr, N, nch);
    csr_blockscan_kernel<<<NT * nch, blk, 0, stream>>>(deg, csum, rowptr, cur, N, nch);
    csr_fill_kernel<<<gTE, blk, 0, stream>>>(edge_u, edge_v, cur, col, rowid, N, E);

    // input stage -> FA
    input_fused_kernel<<<nblk, blk, 0, stream>>>(ctrs, feats, in_W1, in_b1,
                                                 seg_W1, seg_b1, in_b2, seg_b2,
                                                 Wcvt, FA, N);

    // 4 fused layers, ping-pong FA <-> FB
    float* Fi = FA;
    float* Fo = FB;
    for (int i = 0; i < NL; ++i) {
        layer_fused_kernel<<<nblk, blk, 0, stream>>>(
            Fi, Fo, Wcvt, i, rowptr, col, rowid, norm_g + (size_t)i * D,
            norm_b + (size_t)i * D, ctr2_b1 + (size_t)i * D,
            ctr2_b2 + (size_t)i * D, N, E);
        float* tmp = Fi; Fi = Fo; Fo = tmp;
    }

    // meta stage -> d_out  (rowid no longer needed)
    meta_fused_kernel<<<nblk, blk, 0, stream>>>(Fi, mark_type, embed, meta_b1,
                                                meta_b2, Wcvt, (float*)d_out, N);
}